// Round 14
// baseline (1172.504 us; speedup 1.0000x reference)
//
#include <hip/hip_runtime.h>
#include <hip/hip_bf16.h>

// All inputs/outputs are float32 (per the reference file's setup_inputs).

typedef __attribute__((ext_vector_type(8))) short bf16x8;
typedef __attribute__((ext_vector_type(8))) unsigned short u16x8;
typedef __attribute__((ext_vector_type(4))) float f32x4;

static __device__ __forceinline__ short f2bf(float f)
{
    unsigned u = __float_as_uint(f);
    unsigned r = u + 0x7FFFu + ((u >> 16) & 1u);   // RNE
    return (short)(r >> 16);
}
static __device__ __forceinline__ float b2f(unsigned short s)
{
    return __uint_as_float((unsigned)s << 16);
}

// 16-lane butterfly sum via DPP (VALU, no DS-pipe traffic).
static __device__ __forceinline__ float dpp_sum16(float x)
{
    x += __int_as_float(__builtin_amdgcn_update_dpp(
        0, __float_as_int(x), 0xB1, 0xF, 0xF, true));   // quad_perm [1,0,3,2]
    x += __int_as_float(__builtin_amdgcn_update_dpp(
        0, __float_as_int(x), 0x4E, 0xF, 0xF, true));   // quad_perm [2,3,0,1]
    x += __int_as_float(__builtin_amdgcn_update_dpp(
        0, __float_as_int(x), 0x141, 0xF, 0xF, true));  // row_half_mirror
    x += __int_as_float(__builtin_amdgcn_update_dpp(
        0, __float_as_int(x), 0x140, 0xF, 0xF, true));  // row_mirror
    return x;
}

// ---------------------------------------------------------------------------
// Weight conversion (4 convs + in_proj -> bf16).
// ---------------------------------------------------------------------------
__global__ __launch_bounds__(256) void wconv_k(const float* __restrict__ w1,
    const float* __restrict__ w2, const float* __restrict__ w3,
    const float* __restrict__ w4, const float* __restrict__ ipw,
    short* __restrict__ wbf)
{
    const int idx = blockIdx.x * 256 + threadIdx.x;  // 0..163839
    if (idx < 147456) {
        const int c = idx / 36864, rem = idx % 36864;
        const int tap = rem >> 12, r2 = rem & 4095;
        const int co = r2 >> 6, ci = r2 & 63;
        const float* src = (c == 0) ? w1 : (c == 1) ? w2 : (c == 2) ? w3 : w4;
        wbf[idx] = f2bf(src[(co * 64 + ci) * 9 + tap]);
    } else {
        const int i2 = idx - 147456;                 // [e][c]
        wbf[idx] = f2bf(ipw[i2]);
    }
}

// ---------------------------------------------------------------------------
// MFMA 3x3 SAME conv, 64->64 ch, NCHW. Block = one (b,h) row, 256 threads.
// Optional instats: apply InstanceNorm+LeakyReLU to the input during staging
// (stats = [s1[256], s2[256]] by b*64+c; padding stays zero).
// Optional outstats: epilogue accumulates per-(b,co) sum/sumsq via DPP row
// reduction + atomicAdd (stats of output incl. bias and addsrc).
// ---------------------------------------------------------------------------
__global__ __launch_bounds__(256) void conv3x3_mfma_k(const float* __restrict__ in,
    const short* __restrict__ wtap, const float* __restrict__ bias,
    const float* __restrict__ addsrc, const float* __restrict__ instats,
    float* __restrict__ outstats, float* __restrict__ out)
{
    const int bh = blockIdx.x;
    const int b = bh >> 6, h = bh & 63;
    const int t = threadIdx.x;
    __shared__ __align__(16) short lin[3 * 66 * 72];  // [r][w+1][ci]
    {
        const int ci = t >> 2, w16 = (t & 3) * 16;
        float mu = 0.f, rstd = 1.f;
        if (instats) {
            const float S1 = instats[(b << 6) + ci];
            const float S2 = instats[256 + (b << 6) + ci];
            mu = S1 * (1.f / 4096.f);
            rstd = rsqrtf(S2 * (1.f / 4096.f) - mu * mu + 1e-5f);
        }
#pragma unroll
        for (int r = 0; r < 3; ++r) {
            const int hh = h - 1 + r;
            const bool ok = (hh >= 0 && hh < 64);
            const float* src = in + ((size_t)(b * 64 + ci) * 64 + (ok ? hh : 0)) * 64 + w16;
#pragma unroll
            for (int q = 0; q < 4; ++q) {
                float4 v = make_float4(0.f, 0.f, 0.f, 0.f);
                if (ok) {
                    v = *(const float4*)(src + q * 4);
                    if (instats) {
#define NRM(E) { float nv = (v.E - mu) * rstd; v.E = (nv >= 0.f) ? nv : 0.2f * nv; }
                        NRM(x) NRM(y) NRM(z) NRM(w)
#undef NRM
                    }
                }
                const int wb = w16 + q * 4;
                lin[(r * 66 + wb + 1) * 72 + ci] = f2bf(v.x);
                lin[(r * 66 + wb + 2) * 72 + ci] = f2bf(v.y);
                lin[(r * 66 + wb + 3) * 72 + ci] = f2bf(v.z);
                lin[(r * 66 + wb + 4) * 72 + ci] = f2bf(v.w);
            }
        }
        // pad columns w=0 and w=65
        if (t < 216) {
            const int r3 = t / 72, rem = t % 72;
            const int colp = (rem >= 36) ? 65 : 0, ci2 = rem % 36;
            ((int*)lin)[(r3 * 66 + colp) * 36 + ci2] = 0;
        }
    }
    __syncthreads();
    const int lane = t & 63, ct = t >> 6;     // wave = co-tile
    const int n16 = lane & 15, quad = lane >> 4;
    f32x4 acc0 = {0.f, 0.f, 0.f, 0.f};
    f32x4 acc1 = {0.f, 0.f, 0.f, 0.f};
    f32x4 acc2 = {0.f, 0.f, 0.f, 0.f};
    f32x4 acc3 = {0.f, 0.f, 0.f, 0.f};
#pragma unroll
    for (int tap = 0; tap < 9; ++tap) {
        const int dy = tap / 3, dx = tap % 3;
#pragma unroll
        for (int kh = 0; kh < 2; ++kh) {
            const int kk = kh * 32;
            const bf16x8 a = *(const bf16x8*)(wtap +
                ((size_t)tap * 64 + ct * 16 + n16) * 64 + kk + quad * 8);
            const int rb = (dy * 66 + n16 + dx) * 72 + kk + quad * 8;
            const bf16x8 b0 = *(const bf16x8*)&lin[rb + 0 * 16 * 72];
            const bf16x8 b1 = *(const bf16x8*)&lin[rb + 1 * 16 * 72];
            const bf16x8 b2 = *(const bf16x8*)&lin[rb + 2 * 16 * 72];
            const bf16x8 b3 = *(const bf16x8*)&lin[rb + 3 * 16 * 72];
            acc0 = __builtin_amdgcn_mfma_f32_16x16x32_bf16(a, b0, acc0, 0, 0, 0);
            acc1 = __builtin_amdgcn_mfma_f32_16x16x32_bf16(a, b1, acc1, 0, 0, 0);
            acc2 = __builtin_amdgcn_mfma_f32_16x16x32_bf16(a, b2, acc2, 0, 0, 0);
            acc3 = __builtin_amdgcn_mfma_f32_16x16x32_bf16(a, b3, acc3, 0, 0, 0);
        }
    }
#pragma unroll
    for (int r = 0; r < 4; ++r) {
        const int co = ct * 16 + quad * 4 + r;
        const float bv = bias[co];
        float* orow = out + ((size_t)(b * 64 + co) * 64 + h) * 64;
        float v0 = acc0[r] + bv, v1 = acc1[r] + bv, v2 = acc2[r] + bv, v3 = acc3[r] + bv;
        if (addsrc) {
            const float* arow = addsrc + ((size_t)(b * 64 + co) * 64 + h) * 64;
            v0 += arow[n16]; v1 += arow[16 + n16];
            v2 += arow[32 + n16]; v3 += arow[48 + n16];
        }
        if (outstats) {
            float ss = (v0 + v1) + (v2 + v3);
            float qq = fmaf(v0, v0, fmaf(v1, v1, fmaf(v2, v2, v3 * v3)));
            ss = dpp_sum16(ss);
            qq = dpp_sum16(qq);
            if (n16 == 0) {
                atomicAdd(&outstats[(b << 6) + co], ss);
                atomicAdd(&outstats[256 + (b << 6) + co], qq);
            }
        }
        orow[n16] = v0; orow[16 + n16] = v1;
        orow[32 + n16] = v2; orow[48 + n16] = v3;
    }
}

// ---------------------------------------------------------------------------
// Final InstanceNorm apply (stats precomputed in cb's epilogue) + LeakyReLU.
// Block per (b,c), single read pass.
// ---------------------------------------------------------------------------
__global__ __launch_bounds__(256) void inorm_apply_k(const float* __restrict__ in,
    const float* __restrict__ stats, float* __restrict__ out)
{
    const int bc = blockIdx.x;
    const float S1 = stats[bc], S2 = stats[256 + bc];
    const float mu = S1 * (1.f / 4096.f);
    const float rstd = rsqrtf(S2 * (1.f / 4096.f) - mu * mu + 1e-5f);
    const float* row = in + (size_t)bc * 4096;
    float* orow = out + (size_t)bc * 4096;
    for (int i = threadIdx.x; i < 4096; i += 256) {
        float v = (row[i] - mu) * rstd;
        orow[i] = (v >= 0.f) ? v : 0.2f * v;
    }
}

// ---------------------------------------------------------------------------
// LayerNorm over 64 ch + in_proj (256x64) via MFMA. Block = 32 positions.
// ---------------------------------------------------------------------------
__global__ __launch_bounds__(256) void ln_inproj_mfma_k(const float* __restrict__ x1,
    const float* __restrict__ g, const float* __restrict__ be,
    const short* __restrict__ wip, float* __restrict__ xin_raw,
    float* __restrict__ z)
{
    const int bx = blockIdx.x;
    const int b = bx >> 7, l0 = (bx & 127) * 32;
    const int t = threadIdx.x;
    __shared__ __align__(16) short ltile[32 * 72];   // [pos][c]
    __shared__ float ztile[32 * 140];                // [pos][d], pad 140
    {
        const int j = t & 31, gg = t >> 5;           // pos, c-group
        float xr[64];
        float s1 = 0.f, s2 = 0.f;
#pragma unroll
        for (int c = 0; c < 64; ++c) {
            const float v = x1[(b * 64 + c) * 4096 + l0 + j];
            xr[c] = v; s1 += v; s2 = fmaf(v, v, s2);
        }
        const float mu = s1 * (1.f / 64.f);
        const float var = s2 * (1.f / 64.f) - mu * mu;
        const float rstd = rsqrtf(var + 1e-5f);
#pragma unroll
        for (int i = 0; i < 8; ++i) {
            const int c = gg * 8 + i;
            ltile[j * 72 + c] = f2bf((xr[c] - mu) * rstd * g[c] + be[c]);
        }
    }
    __syncthreads();
    const int lane = t & 63, wv = t >> 6;
    const int n16 = lane & 15, quad = lane >> 4;
    f32x4 acc[4][2];
#pragma unroll
    for (int i = 0; i < 4; ++i)
#pragma unroll
        for (int p = 0; p < 2; ++p) acc[i][p] = (f32x4){0.f, 0.f, 0.f, 0.f};
#pragma unroll
    for (int i = 0; i < 4; ++i) {
        const int cot = wv * 4 + i;                  // co-tile 0..15
#pragma unroll
        for (int kh = 0; kh < 2; ++kh) {
            const bf16x8 a = *(const bf16x8*)(wip +
                (size_t)(cot * 16 + n16) * 64 + kh * 32 + quad * 8);
#pragma unroll
            for (int p = 0; p < 2; ++p) {
                const bf16x8 bb = *(const bf16x8*)&ltile[
                    (p * 16 + n16) * 72 + kh * 32 + quad * 8];
                acc[i][p] = __builtin_amdgcn_mfma_f32_16x16x32_bf16(a, bb, acc[i][p], 0, 0, 0);
            }
        }
    }
#pragma unroll
    for (int i = 0; i < 4; ++i) {
        const int cot = wv * 4 + i;
#pragma unroll
        for (int p = 0; p < 2; ++p) {
            const int pos = p * 16 + n16;
#pragma unroll
            for (int r = 0; r < 4; ++r) {
                const int e = cot * 16 + quad * 4 + r;
                const float v = acc[i][p][r];
                if (e < 128) xin_raw[((size_t)(b * 128 + e)) * 4096 + l0 + pos] = v;
                else ztile[pos * 140 + (e - 128)] = v;
            }
        }
    }
    __syncthreads();
    {
        const int pos = t >> 3, d0 = (t & 7) * 16;
        float* dst = z + ((size_t)(b * 4096 + l0 + pos)) * 128 + d0;
        const float* srcz = ztile + pos * 140 + d0;
#pragma unroll
        for (int q = 0; q < 4; ++q)
            *(float4*)(dst + q * 4) = *(const float4*)(srcz + q * 4);
    }
}

// ---------------------------------------------------------------------------
// Depthwise 3x3 SAME conv + bias + SiLU, fused with spatial transpose.
// ---------------------------------------------------------------------------
__global__ __launch_bounds__(256) void dwconv_silu_T_k(const float* __restrict__ in,
    const float* __restrict__ w, const float* __restrict__ bias,
    float* __restrict__ xin_s, float* __restrict__ xin_T)
{
    const int bd = blockIdx.x;                       // b*128 + d
    const int d = bd & 127;
    const int t = threadIdx.x;
    __shared__ float pin[64 * 65], pout[64 * 65];
    const float* src = in + (size_t)bd * 4096;
#pragma unroll
    for (int i = 0; i < 16; ++i) {
        const int e = i * 256 + t;
        pin[(e >> 6) * 65 + (e & 63)] = src[e];
    }
    __syncthreads();
    const float w0 = w[d * 9 + 0], w1 = w[d * 9 + 1], w2 = w[d * 9 + 2];
    const float w3 = w[d * 9 + 3], w4 = w[d * 9 + 4], w5 = w[d * 9 + 5];
    const float w6 = w[d * 9 + 6], w7 = w[d * 9 + 7], w8 = w[d * 9 + 8];
    const float bv = bias[d];
    float* outs = xin_s + (size_t)bd * 4096;
#pragma unroll
    for (int i = 0; i < 16; ++i) {
        const int e = i * 256 + t;
        const int hh = e >> 6, ww = e & 63;
        float acc = bv;
        const bool h0 = hh > 0, h1 = hh < 63, v0 = ww > 0, v1 = ww < 63;
        const float* rm = pin + (hh - 1) * 65;
        const float* rc = pin + hh * 65;
        const float* rp = pin + (hh + 1) * 65;
        if (h0) {
            if (v0) acc = fmaf(rm[ww - 1], w0, acc);
            acc = fmaf(rm[ww], w1, acc);
            if (v1) acc = fmaf(rm[ww + 1], w2, acc);
        }
        if (v0) acc = fmaf(rc[ww - 1], w3, acc);
        acc = fmaf(rc[ww], w4, acc);
        if (v1) acc = fmaf(rc[ww + 1], w5, acc);
        if (h1) {
            if (v0) acc = fmaf(rp[ww - 1], w6, acc);
            acc = fmaf(rp[ww], w7, acc);
            if (v1) acc = fmaf(rp[ww + 1], w8, acc);
        }
        const float val = acc / (1.f + __expf(-acc));
        pout[hh * 65 + ww] = val;
        outs[e] = val;
    }
    __syncthreads();
    float* outT = xin_T + (size_t)bd * 4096;
#pragma unroll
    for (int i = 0; i < 16; ++i) {
        const int e = i * 256 + t;
        const int wi = e >> 6, hi = e & 63;
        outT[e] = pout[hi * 65 + wi];
    }
}

// ---------------------------------------------------------------------------
// x_dbl[b,k,c,m] = sum_d xs[b,k,d,m] * x_proj_w[k,c,d]  (c=36, scan order m).
// ---------------------------------------------------------------------------
__global__ __launch_bounds__(256) void xdbl_k(const float* __restrict__ xin_s,
    const float* __restrict__ xin_T, const float* __restrict__ xpw,
    float* __restrict__ xdbl)
{
    const int bx = blockIdx.x;
    const int bk = bx >> 7, m0 = (bx & 127) * 32;
    const int b = bk >> 2, k = bk & 3;
    __shared__ float tl[32 * 132];   // [j][d], pad 132
    const float* src = (k & 1) ? xin_T : xin_s;
    const bool rev = (k >= 2);
    for (int e = threadIdx.x; e < 4096; e += 256) {
        const int d = e >> 5, j = e & 31;
        const int m = m0 + j;
        const int um = rev ? (4095 - m) : m;
        tl[j * 132 + d] = src[(b * 128 + d) * 4096 + um];
    }
    __syncthreads();
    const int j = threadIdx.x & 31, c0 = threadIdx.x >> 5;
    const float4* xv4 = (const float4*)(tl + j * 132);
    float acc[5] = {0.f, 0.f, 0.f, 0.f, 0.f};
    for (int d4 = 0; d4 < 32; ++d4) {
        const float4 xv = xv4[d4];
#pragma unroll
        for (int q = 0; q < 5; ++q) {
            const int c = c0 + q * 8;
            if (c < 36) {
                const float4 wv = *(const float4*)&xpw[((size_t)(k * 36 + c)) * 128 + d4 * 4];
                acc[q] = fmaf(xv.x, wv.x, acc[q]);
                acc[q] = fmaf(xv.y, wv.y, acc[q]);
                acc[q] = fmaf(xv.z, wv.z, acc[q]);
                acc[q] = fmaf(xv.w, wv.w, acc[q]);
            }
        }
    }
#pragma unroll
    for (int q = 0; q < 5; ++q) {
        const int c = c0 + q * 8;
        if (c < 36) xdbl[((size_t)bk * 36 + c) * 4096 + m0 + j] = acc[q];
    }
}

// ---------------------------------------------------------------------------
// Single-pass segmented scan with decoupled lookback (rocPRIM pattern).
// Grid: bx = bk*512 + d8*64 + seg (seg in LSBs = ascending dispatch order).
// Stage once (64 steps, LDS); local zero-start summary (hl, prod);
// publish aggregate (flag=1, agent-scope release); look back through
// predecessors for h_start; publish inclusive (flag=2); replay for y.
// ---------------------------------------------------------------------------
__global__ __launch_bounds__(256) void scan_fused_k(const float* __restrict__ xdbl,
    const float* __restrict__ xin_s, const float* __restrict__ xin_T,
    const float* __restrict__ A_logs, const float* __restrict__ dtw,
    const float* __restrict__ dtb, const float* __restrict__ Dsp,
    float* __restrict__ aggH, float* __restrict__ aggP,
    float* __restrict__ inclH, int* __restrict__ flags,
    unsigned short* __restrict__ ybuf)
{
    const int bx = blockIdx.x;
    const int seg = bx & 63, d8 = (bx >> 6) & 7, bk = bx >> 9;
    const int b = bk >> 2, k = bk & 3;
    const int t = threadIdx.x;
    const int chain = t >> 4, n = t & 15;
    const int d = d8 * 16 + chain;
    const float A = -__expf(A_logs[(k * 128 + d) * 16 + n]);
    __shared__ float sB[16 * 68], sC[16 * 68], sdt[16 * 68], su[16 * 68];
    __shared__ float sy[64 * 16];   // [j][dd]
    __shared__ int sflag;
    const float* srcu = (k & 1) ? xin_T : xin_s;
    const bool rev = (k >= 2);
    const int col = t & 63, r0 = t >> 6;
    const int m0 = seg * 64;
    const float Dk0 = (k == 0)
        ? (Dsp[d] + Dsp[128 + d] + Dsp[256 + d] + Dsp[384 + d]) : 0.f;
    // ---- stage once ----
    {
        const float dts0 = xdbl[((size_t)bk * 36 + 0) * 4096 + m0 + col];
        const float dts1 = xdbl[((size_t)bk * 36 + 1) * 4096 + m0 + col];
        const float dts2 = xdbl[((size_t)bk * 36 + 2) * 4096 + m0 + col];
        const float dts3 = xdbl[((size_t)bk * 36 + 3) * 4096 + m0 + col];
        const int m = m0 + col;
        const int um = rev ? (4095 - m) : m;
#pragma unroll
        for (int i = 0; i < 4; ++i) {
            const int nn = r0 + 4 * i;
            sB[nn * 68 + col] = xdbl[((size_t)bk * 36 + 4 + nn) * 4096 + m0 + col];
            sC[nn * 68 + col] = xdbl[((size_t)bk * 36 + 20 + nn) * 4096 + m0 + col];
            const int dd = d8 * 16 + nn;
            const float* wp = dtw + (k * 128 + dd) * 4;
            float s = dtb[k * 128 + dd];
            s = fmaf(dts0, wp[0], s);
            s = fmaf(dts1, wp[1], s);
            s = fmaf(dts2, wp[2], s);
            s = fmaf(dts3, wp[3], s);
            const float sp = (s > 20.f) ? s : log1pf(__expf(s));
            sdt[nn * 68 + col] = sp;
            const float uval = srcu[(b * 128 + dd) * 4096 + um];
            su[nn * 68 + col] = (k == 0) ? uval : sp * uval;   // u or du
        }
    }
    __syncthreads();
    const float4* B4  = (const float4*)(sB + n * 68);
    const float4* C4  = (const float4*)(sC + n * 68);
    const float4* dt4 = (const float4*)(sdt + chain * 68);
    const float4* u4  = (const float4*)(su + chain * 68);
    // ---- local zero-start summary ----
    float hl = 0.f, pl = 1.f;
    if (k == 0) {
#pragma unroll 4
        for (int q = 0; q < 16; ++q) {
            const float4 dt = dt4[q], uu = u4[q], BB = B4[q];
            float a;
            a = __expf(dt.x * A); hl = fmaf(hl, a, dt.x * uu.x * BB.x); pl *= a;
            a = __expf(dt.y * A); hl = fmaf(hl, a, dt.y * uu.y * BB.y); pl *= a;
            a = __expf(dt.z * A); hl = fmaf(hl, a, dt.z * uu.z * BB.z); pl *= a;
            a = __expf(dt.w * A); hl = fmaf(hl, a, dt.w * uu.w * BB.w); pl *= a;
        }
    } else {
#pragma unroll 4
        for (int q = 0; q < 16; ++q) {
            const float4 dt = dt4[q], du = u4[q], BB = B4[q];
            float a;
            a = __expf(dt.x * A); hl = fmaf(hl, a, du.x * BB.x); pl *= a;
            a = __expf(dt.y * A); hl = fmaf(hl, a, du.y * BB.y); pl *= a;
            a = __expf(dt.z * A); hl = fmaf(hl, a, du.z * BB.z); pl *= a;
            a = __expf(dt.w * A); hl = fmaf(hl, a, du.w * BB.w); pl *= a;
        }
    }
    // ---- publish aggregate / lookback / publish inclusive ----
    const size_t sidx = (size_t)bx * 256 + t;
    float hs = 0.f;
    if (seg == 0) {
        __hip_atomic_store(&inclH[sidx], hl, __ATOMIC_RELAXED, __HIP_MEMORY_SCOPE_AGENT);
        __syncthreads();
        if (t == 0)
            __hip_atomic_store(&flags[bx], 2, __ATOMIC_RELEASE, __HIP_MEMORY_SCOPE_AGENT);
    } else {
        __hip_atomic_store(&aggH[sidx], hl, __ATOMIC_RELAXED, __HIP_MEMORY_SCOPE_AGENT);
        __hip_atomic_store(&aggP[sidx], pl, __ATOMIC_RELAXED, __HIP_MEMORY_SCOPE_AGENT);
        __syncthreads();
        if (t == 0)
            __hip_atomic_store(&flags[bx], 1, __ATOMIC_RELEASE, __HIP_MEMORY_SCOPE_AGENT);
        // lookback
        const int base = bx - seg;
        int s = seg - 1;
        float hr = 0.f, prr = 1.f;
        for (;;) {
            if (t == 0) {
                int f;
                for (;;) {
                    f = __hip_atomic_load(&flags[base + s], __ATOMIC_ACQUIRE,
                                          __HIP_MEMORY_SCOPE_AGENT);
                    if (f != 0) break;
                    __builtin_amdgcn_s_sleep(8);
                }
                sflag = f;
            }
            __syncthreads();
            const int f = sflag;
            __syncthreads();
            const size_t pidx = (size_t)(base + s) * 256 + t;
            if (f == 2) {
                const float hi = __hip_atomic_load(&inclH[pidx], __ATOMIC_RELAXED,
                                                   __HIP_MEMORY_SCOPE_AGENT);
                hr = fmaf(prr, hi, hr);
                break;
            } else {
                const float ha = __hip_atomic_load(&aggH[pidx], __ATOMIC_RELAXED,
                                                   __HIP_MEMORY_SCOPE_AGENT);
                const float pa = __hip_atomic_load(&aggP[pidx], __ATOMIC_RELAXED,
                                                   __HIP_MEMORY_SCOPE_AGENT);
                hr = fmaf(prr, ha, hr);
                prr *= pa;
                --s;
            }
        }
        hs = hr;
        const float hincl = fmaf(pl, hs, hl);
        __hip_atomic_store(&inclH[sidx], hincl, __ATOMIC_RELAXED, __HIP_MEMORY_SCOPE_AGENT);
        __syncthreads();
        if (t == 0)
            __hip_atomic_store(&flags[bx], 2, __ATOMIC_RELEASE, __HIP_MEMORY_SCOPE_AGENT);
    }
    // ---- replay with h_start, emit y ----
    float h = hs;
    if (k == 0) {
#pragma unroll 4
        for (int q = 0; q < 16; ++q) {
            const float4 dt = dt4[q], uu = u4[q], BB = B4[q], CC = C4[q];
            float a, p;
#define SCAN_STEP(E, IDX)                                                     \
            a = __expf(dt.E * A);                                             \
            h = fmaf(h, a, dt.E * uu.E * BB.E);                               \
            p = dpp_sum16(h * CC.E);                                          \
            if (n == 0) {                                                     \
                const int jg = q * 4 + IDX;                                   \
                sy[jg * 16 + chain] = fmaf(Dk0, uu.E, p);                     \
            }
            SCAN_STEP(x, 0)
            SCAN_STEP(y, 1)
            SCAN_STEP(z, 2)
            SCAN_STEP(w, 3)
#undef SCAN_STEP
        }
    } else {
#pragma unroll 4
        for (int q = 0; q < 16; ++q) {
            const float4 dt = dt4[q], du = u4[q], BB = B4[q], CC = C4[q];
            float a, p;
#define SCAN_STEP(E, IDX)                                                     \
            a = __expf(dt.E * A);                                             \
            h = fmaf(h, a, du.E * BB.E);                                      \
            p = dpp_sum16(h * CC.E);                                          \
            if (n == 0) {                                                     \
                const int jg = q * 4 + IDX;                                   \
                sy[jg * 16 + chain] = p;                                      \
            }
            SCAN_STEP(x, 0)
            SCAN_STEP(y, 1)
            SCAN_STEP(z, 2)
            SCAN_STEP(w, 3)
#undef SCAN_STEP
        }
    }
    __syncthreads();
    const int ddl = t & 15;
    const int dg = d8 * 16 + ddl;
    unsigned short* yk = ybuf + (size_t)(k * 4 + b) * 4096 * 128;
#pragma unroll
    for (int p2 = 0; p2 < 4; ++p2) {
        const int e = p2 * 256 + t;
        const int j = e >> 4;               // 0..63
        const int m = m0 + j;
        int l;
        if (k == 0) l = m;
        else if (k == 1) l = ((m & 63) << 6) | (m >> 6);
        else if (k == 2) l = 4095 - m;
        else { const int mf = 4095 - m; l = ((mf & 63) << 6) | (mf >> 6); }
        yk[(size_t)l * 128 + dg] = (unsigned short)f2bf(sy[j * 16 + ddl]);
    }
}

// ---------------------------------------------------------------------------
// Finalize: v[d] = sum_k ybuf[k][b][l][d] (bf16); LN over 128; * silu(z);
// out_proj GEMV; LDS-transposed coalesced store + skip*x1. Block = 32 l.
// ---------------------------------------------------------------------------
__global__ __launch_bounds__(256) void finalize_k(const unsigned short* __restrict__ ybuf,
    const float* __restrict__ z, const float* __restrict__ x1,
    const float* __restrict__ ong, const float* __restrict__ onb,
    const float* __restrict__ opw, const float* __restrict__ skipp,
    float* __restrict__ res)
{
    const int bx = blockIdx.x;               // b*128 + tile
    const int b = bx >> 7, l0 = (bx & 127) * 32;
    const int t = threadIdx.x;
    const int j = t & 31, g = t >> 5;        // g 0..7
    const int l = l0 + j;
    const u16x8* y0p = (const u16x8*)(ybuf + ((size_t)(0 + b) * 4096 + l) * 128);
    const u16x8* y1p = (const u16x8*)(ybuf + ((size_t)(4 + b) * 4096 + l) * 128);
    const u16x8* y2p = (const u16x8*)(ybuf + ((size_t)(8 + b) * 4096 + l) * 128);
    const u16x8* y3p = (const u16x8*)(ybuf + ((size_t)(12 + b) * 4096 + l) * 128);
    float vr[128];
    float s1 = 0.f, s2 = 0.f;
#pragma unroll
    for (int g8 = 0; g8 < 16; ++g8) {
        const u16x8 a0 = y0p[g8], a1 = y1p[g8], a2 = y2p[g8], a3 = y3p[g8];
#pragma unroll
        for (int e = 0; e < 8; ++e) {
            const float f = (b2f(a0[e]) + b2f(a1[e])) + (b2f(a2[e]) + b2f(a3[e]));
            vr[g8 * 8 + e] = f;
            s1 += f; s2 = fmaf(f, f, s2);
        }
    }
    const float mu = s1 * (1.f / 128.f);
    const float var = s2 * (1.f / 128.f) - mu * mu;
    const float rstd = rsqrtf(var + 1e-5f);
    const float4* zp = (const float4*)(z + ((size_t)(b * 4096 + l)) * 128);
    const float4* gp = (const float4*)ong;
    const float4* bp = (const float4*)onb;
#pragma unroll
    for (int d4 = 0; d4 < 32; ++d4) {
        const float4 gg = gp[d4], bb = bp[d4], zz = zp[d4];
#define GATE(E, IDX)                                                          \
        {                                                                     \
            const float yln = (vr[d4 * 4 + IDX] - mu) * rstd * gg.E + bb.E;   \
            vr[d4 * 4 + IDX] = yln * (zz.E / (1.f + __expf(-zz.E)));          \
        }
        GATE(x, 0) GATE(y, 1) GATE(z, 2) GATE(w, 3)
#undef GATE
    }
    float acc[8] = {0.f, 0.f, 0.f, 0.f, 0.f, 0.f, 0.f, 0.f};
    for (int d4 = 0; d4 < 32; ++d4) {
#pragma unroll
        for (int q = 0; q < 8; ++q) {
            const float4 wv = *(const float4*)&opw[(size_t)(g * 8 + q) * 128 + d4 * 4];
            acc[q] = fmaf(vr[d4 * 4 + 0], wv.x, acc[q]);
            acc[q] = fmaf(vr[d4 * 4 + 1], wv.y, acc[q]);
            acc[q] = fmaf(vr[d4 * 4 + 2], wv.z, acc[q]);
            acc[q] = fmaf(vr[d4 * 4 + 3], wv.w, acc[q]);
        }
    }
    __shared__ float sres[64 * 33];
#pragma unroll
    for (int q = 0; q < 8; ++q) sres[(g * 8 + q) * 33 + j] = acc[q];
    __syncthreads();
    const float sk = skipp[0];
    for (int e = t; e < 2048; e += 256) {
        const int co = e >> 5, jj = e & 31;
        const size_t o = ((size_t)(b * 64 + co)) * 4096 + l0 + jj;
        res[o] = sres[co * 33 + jj] + sk * x1[o];
    }
}

// ---------------------------------------------------------------------------
// Workspace layout (floats), ~77.4 MB:
//   x1 @0 (1M), xin_s @1M (2M), zbuf @3M (2M), xin_T @5M (2M),
//   xdbl @7,340,032 (2,359,296), ybuf @9,699,328 (bf16, 4M float-slots),
//   aggH @13,893,632 (2M), aggP @15,990,784 (2M),
//   G @18,087,936 (2M): conv chain / xin_raw / inclH / res+tmp,
//   wbf @20,185,088 (81,920), flags @20,267,008 (8192 ints),
//   stats @20,275,200 (1024: conv1 s1/s2 @0/256, cb s1/s2 @512/768)
// ---------------------------------------------------------------------------
extern "C" void kernel_launch(void* const* d_in, const int* in_sizes, int n_in,
                              void* d_out, int out_size, void* d_ws, size_t ws_size,
                              hipStream_t stream)
{
    const float* x          = (const float*)d_in[0];
    const float* conv1_w    = (const float*)d_in[1];
    const float* conv1_b    = (const float*)d_in[2];
    const float* conv2_w    = (const float*)d_in[3];
    const float* conv2_b    = (const float*)d_in[4];
    const float* cf_w       = (const float*)d_in[5];
    const float* cf_b       = (const float*)d_in[6];
    const float* ln_g       = (const float*)d_in[7];
    const float* ln_b       = (const float*)d_in[8];
    const float* in_proj_w  = (const float*)d_in[9];
    const float* dw_w       = (const float*)d_in[10];
    const float* dw_b       = (const float*)d_in[11];
    const float* x_proj_w   = (const float*)d_in[12];
    const float* dt_proj_w  = (const float*)d_in[13];
    const float* dt_proj_b  = (const float*)d_in[14];
    const float* A_logs     = (const float*)d_in[15];
    const float* Ds         = (const float*)d_in[16];
    const float* out_norm_g = (const float*)d_in[17];
    const float* out_norm_b = (const float*)d_in[18];
    const float* out_proj_w = (const float*)d_in[19];
    const float* skip_scale = (const float*)d_in[20];
    const float* cb_w       = (const float*)d_in[21];
    const float* cb_b       = (const float*)d_in[22];

    float* ws = (float*)d_ws;
    float* x1    = ws;                 // 1,048,576
    float* xin_s = ws + 1048576;       // 2,097,152
    float* zbuf  = ws + 3145728;       // 2,097,152
    float* xin_T = ws + 5242880;       // 2,097,152
    float* xdbl  = ws + 7340032;       // 2,359,296
    unsigned short* ybuf = (unsigned short*)(ws + 9699328);  // bf16 [k][b][l][d]
    float* aggH  = ws + 13893632;      // 2,097,152
    float* aggP  = ws + 15990784;      // 2,097,152
    float* G     = ws + 18087936;      // 2,097,152: conv chain / xin_raw / inclH / res
    float* G0 = G;
    float* G1 = G + 1048576;
    short* wbf  = (short*)(ws + 20185088);  // 163,840 bf16
    short* wbf1 = wbf;
    short* wbf2 = wbf + 36864;
    short* wbf3 = wbf + 73728;
    short* wbf4 = wbf + 110592;
    short* wip  = wbf + 147456;
    int*   flags  = (int*)(ws + 20267008);   // 8192
    float* stats1 = ws + 20275200;           // 512 (conv1 out stats)
    float* stats2 = ws + 20275712;           // 512 (cb out stats)

    // zero flags + both stats buffers (contiguous 9216 floats = 36 KB)
    hipMemsetAsync(flags, 0, 9216 * sizeof(float), stream);

    wconv_k<<<640, 256, 0, stream>>>(conv1_w, conv2_w, cf_w, cb_w, in_proj_w, wbf);

    conv3x3_mfma_k<<<256, 256, 0, stream>>>(x, wbf1, conv1_b, nullptr,
                                            nullptr, stats1, G0);
    conv3x3_mfma_k<<<256, 256, 0, stream>>>(G0, wbf2, conv2_b, nullptr,
                                            stats1, nullptr, G1);
    conv3x3_mfma_k<<<256, 256, 0, stream>>>(G1, wbf3, cf_b, nullptr,
                                            nullptr, nullptr, x1);
    ln_inproj_mfma_k<<<512, 256, 0, stream>>>(x1, ln_g, ln_b, wip, G /*xin_raw*/, zbuf);
    dwconv_silu_T_k<<<512, 256, 0, stream>>>(G /*xin_raw*/, dw_w, dw_b, xin_s, xin_T);
    xdbl_k<<<2048, 256, 0, stream>>>(xin_s, xin_T, x_proj_w, xdbl);
    scan_fused_k<<<8192, 256, 0, stream>>>(xdbl, xin_s, xin_T, A_logs, dt_proj_w,
                                           dt_proj_b, Ds, aggH, aggP,
                                           G /*inclH*/, flags, ybuf);
    finalize_k<<<512, 256, 0, stream>>>(ybuf, zbuf, x1, out_norm_g, out_norm_b,
                                        out_proj_w, skip_scale, G0 /*res*/);
    conv3x3_mfma_k<<<256, 256, 0, stream>>>(G0 /*res*/, wbf4, cb_b, x1,
                                            nullptr, stats2, G1 /*tmp*/);
    inorm_apply_k<<<256, 256, 0, stream>>>(G1 /*tmp*/, stats2, (float*)d_out);
}

// Round 15
// 386.918 us; speedup vs baseline: 3.0304x; 3.0304x over previous
//
#include <hip/hip_runtime.h>
#include <hip/hip_bf16.h>

// All inputs/outputs are float32 (per the reference file's setup_inputs).

typedef __attribute__((ext_vector_type(8))) short bf16x8;
typedef __attribute__((ext_vector_type(8))) unsigned short u16x8;
typedef __attribute__((ext_vector_type(4))) float f32x4;

static __device__ __forceinline__ short f2bf(float f)
{
    unsigned u = __float_as_uint(f);
    unsigned r = u + 0x7FFFu + ((u >> 16) & 1u);   // RNE
    return (short)(r >> 16);
}
static __device__ __forceinline__ float b2f(unsigned short s)
{
    return __uint_as_float((unsigned)s << 16);
}

// 16-lane butterfly sum via DPP (VALU, no DS-pipe traffic).
static __device__ __forceinline__ float dpp_sum16(float x)
{
    x += __int_as_float(__builtin_amdgcn_update_dpp(
        0, __float_as_int(x), 0xB1, 0xF, 0xF, true));   // quad_perm [1,0,3,2]
    x += __int_as_float(__builtin_amdgcn_update_dpp(
        0, __float_as_int(x), 0x4E, 0xF, 0xF, true));   // quad_perm [2,3,0,1]
    x += __int_as_float(__builtin_amdgcn_update_dpp(
        0, __float_as_int(x), 0x141, 0xF, 0xF, true));  // row_half_mirror
    x += __int_as_float(__builtin_amdgcn_update_dpp(
        0, __float_as_int(x), 0x140, 0xF, 0xF, true));  // row_mirror
    return x;
}

// ---------------------------------------------------------------------------
// Weight conversion (4 convs + in_proj -> bf16).
// ---------------------------------------------------------------------------
__global__ __launch_bounds__(256) void wconv_k(const float* __restrict__ w1,
    const float* __restrict__ w2, const float* __restrict__ w3,
    const float* __restrict__ w4, const float* __restrict__ ipw,
    short* __restrict__ wbf)
{
    const int idx = blockIdx.x * 256 + threadIdx.x;  // 0..163839
    if (idx < 147456) {
        const int c = idx / 36864, rem = idx % 36864;
        const int tap = rem >> 12, r2 = rem & 4095;
        const int co = r2 >> 6, ci = r2 & 63;
        const float* src = (c == 0) ? w1 : (c == 1) ? w2 : (c == 2) ? w3 : w4;
        wbf[idx] = f2bf(src[(co * 64 + ci) * 9 + tap]);
    } else {
        const int i2 = idx - 147456;                 // [e][c]
        wbf[idx] = f2bf(ipw[i2]);
    }
}

// ---------------------------------------------------------------------------
// MFMA 3x3 SAME conv, 64->64 ch, NCHW. Block = one (b,h) row, 256 threads.
// instats: apply InstanceNorm+LeakyReLU to input during staging.
// outstats: epilogue accumulates per-(b,co) sum/sumsq (DPP + atomicAdd).
// (both verified correct in R14)
// ---------------------------------------------------------------------------
__global__ __launch_bounds__(256) void conv3x3_mfma_k(const float* __restrict__ in,
    const short* __restrict__ wtap, const float* __restrict__ bias,
    const float* __restrict__ addsrc, const float* __restrict__ instats,
    float* __restrict__ outstats, float* __restrict__ out)
{
    const int bh = blockIdx.x;
    const int b = bh >> 6, h = bh & 63;
    const int t = threadIdx.x;
    __shared__ __align__(16) short lin[3 * 66 * 72];  // [r][w+1][ci]
    {
        const int ci = t >> 2, w16 = (t & 3) * 16;
        float mu = 0.f, rstd = 1.f;
        if (instats) {
            const float S1 = instats[(b << 6) + ci];
            const float S2 = instats[256 + (b << 6) + ci];
            mu = S1 * (1.f / 4096.f);
            rstd = rsqrtf(S2 * (1.f / 4096.f) - mu * mu + 1e-5f);
        }
#pragma unroll
        for (int r = 0; r < 3; ++r) {
            const int hh = h - 1 + r;
            const bool ok = (hh >= 0 && hh < 64);
            const float* src = in + ((size_t)(b * 64 + ci) * 64 + (ok ? hh : 0)) * 64 + w16;
#pragma unroll
            for (int q = 0; q < 4; ++q) {
                float4 v = make_float4(0.f, 0.f, 0.f, 0.f);
                if (ok) {
                    v = *(const float4*)(src + q * 4);
                    if (instats) {
#define NRM(E) { float nv = (v.E - mu) * rstd; v.E = (nv >= 0.f) ? nv : 0.2f * nv; }
                        NRM(x) NRM(y) NRM(z) NRM(w)
#undef NRM
                    }
                }
                const int wb = w16 + q * 4;
                lin[(r * 66 + wb + 1) * 72 + ci] = f2bf(v.x);
                lin[(r * 66 + wb + 2) * 72 + ci] = f2bf(v.y);
                lin[(r * 66 + wb + 3) * 72 + ci] = f2bf(v.z);
                lin[(r * 66 + wb + 4) * 72 + ci] = f2bf(v.w);
            }
        }
        if (t < 216) {
            const int r3 = t / 72, rem = t % 72;
            const int colp = (rem >= 36) ? 65 : 0, ci2 = rem % 36;
            ((int*)lin)[(r3 * 66 + colp) * 36 + ci2] = 0;
        }
    }
    __syncthreads();
    const int lane = t & 63, ct = t >> 6;     // wave = co-tile
    const int n16 = lane & 15, quad = lane >> 4;
    f32x4 acc0 = {0.f, 0.f, 0.f, 0.f};
    f32x4 acc1 = {0.f, 0.f, 0.f, 0.f};
    f32x4 acc2 = {0.f, 0.f, 0.f, 0.f};
    f32x4 acc3 = {0.f, 0.f, 0.f, 0.f};
#pragma unroll
    for (int tap = 0; tap < 9; ++tap) {
        const int dy = tap / 3, dx = tap % 3;
#pragma unroll
        for (int kh = 0; kh < 2; ++kh) {
            const int kk = kh * 32;
            const bf16x8 a = *(const bf16x8*)(wtap +
                ((size_t)tap * 64 + ct * 16 + n16) * 64 + kk + quad * 8);
            const int rb = (dy * 66 + n16 + dx) * 72 + kk + quad * 8;
            const bf16x8 b0 = *(const bf16x8*)&lin[rb + 0 * 16 * 72];
            const bf16x8 b1 = *(const bf16x8*)&lin[rb + 1 * 16 * 72];
            const bf16x8 b2 = *(const bf16x8*)&lin[rb + 2 * 16 * 72];
            const bf16x8 b3 = *(const bf16x8*)&lin[rb + 3 * 16 * 72];
            acc0 = __builtin_amdgcn_mfma_f32_16x16x32_bf16(a, b0, acc0, 0, 0, 0);
            acc1 = __builtin_amdgcn_mfma_f32_16x16x32_bf16(a, b1, acc1, 0, 0, 0);
            acc2 = __builtin_amdgcn_mfma_f32_16x16x32_bf16(a, b2, acc2, 0, 0, 0);
            acc3 = __builtin_amdgcn_mfma_f32_16x16x32_bf16(a, b3, acc3, 0, 0, 0);
        }
    }
#pragma unroll
    for (int r = 0; r < 4; ++r) {
        const int co = ct * 16 + quad * 4 + r;
        const float bv = bias[co];
        float* orow = out + ((size_t)(b * 64 + co) * 64 + h) * 64;
        float v0 = acc0[r] + bv, v1 = acc1[r] + bv, v2 = acc2[r] + bv, v3 = acc3[r] + bv;
        if (addsrc) {
            const float* arow = addsrc + ((size_t)(b * 64 + co) * 64 + h) * 64;
            v0 += arow[n16]; v1 += arow[16 + n16];
            v2 += arow[32 + n16]; v3 += arow[48 + n16];
        }
        if (outstats) {
            float ss = (v0 + v1) + (v2 + v3);
            float qq = fmaf(v0, v0, fmaf(v1, v1, fmaf(v2, v2, v3 * v3)));
            ss = dpp_sum16(ss);
            qq = dpp_sum16(qq);
            if (n16 == 0) {
                atomicAdd(&outstats[(b << 6) + co], ss);
                atomicAdd(&outstats[256 + (b << 6) + co], qq);
            }
        }
        orow[n16] = v0; orow[16 + n16] = v1;
        orow[32 + n16] = v2; orow[48 + n16] = v3;
    }
}

// ---------------------------------------------------------------------------
// Final InstanceNorm apply (stats precomputed in cb's epilogue) + LeakyReLU.
// ---------------------------------------------------------------------------
__global__ __launch_bounds__(256) void inorm_apply_k(const float* __restrict__ in,
    const float* __restrict__ stats, float* __restrict__ out)
{
    const int bc = blockIdx.x;
    const float S1 = stats[bc], S2 = stats[256 + bc];
    const float mu = S1 * (1.f / 4096.f);
    const float rstd = rsqrtf(S2 * (1.f / 4096.f) - mu * mu + 1e-5f);
    const float* row = in + (size_t)bc * 4096;
    float* orow = out + (size_t)bc * 4096;
    for (int i = threadIdx.x; i < 4096; i += 256) {
        float v = (row[i] - mu) * rstd;
        orow[i] = (v >= 0.f) ? v : 0.2f * v;
    }
}

// ---------------------------------------------------------------------------
// LayerNorm over 64 ch + in_proj (256x64) via MFMA. Block = 32 positions.
// ---------------------------------------------------------------------------
__global__ __launch_bounds__(256) void ln_inproj_mfma_k(const float* __restrict__ x1,
    const float* __restrict__ g, const float* __restrict__ be,
    const short* __restrict__ wip, float* __restrict__ xin_raw,
    float* __restrict__ z)
{
    const int bx = blockIdx.x;
    const int b = bx >> 7, l0 = (bx & 127) * 32;
    const int t = threadIdx.x;
    __shared__ __align__(16) short ltile[32 * 72];   // [pos][c]
    __shared__ float ztile[32 * 140];                // [pos][d], pad 140
    {
        const int j = t & 31, gg = t >> 5;           // pos, c-group
        float xr[64];
        float s1 = 0.f, s2 = 0.f;
#pragma unroll
        for (int c = 0; c < 64; ++c) {
            const float v = x1[(b * 64 + c) * 4096 + l0 + j];
            xr[c] = v; s1 += v; s2 = fmaf(v, v, s2);
        }
        const float mu = s1 * (1.f / 64.f);
        const float var = s2 * (1.f / 64.f) - mu * mu;
        const float rstd = rsqrtf(var + 1e-5f);
#pragma unroll
        for (int i = 0; i < 8; ++i) {
            const int c = gg * 8 + i;
            ltile[j * 72 + c] = f2bf((xr[c] - mu) * rstd * g[c] + be[c]);
        }
    }
    __syncthreads();
    const int lane = t & 63, wv = t >> 6;
    const int n16 = lane & 15, quad = lane >> 4;
    f32x4 acc[4][2];
#pragma unroll
    for (int i = 0; i < 4; ++i)
#pragma unroll
        for (int p = 0; p < 2; ++p) acc[i][p] = (f32x4){0.f, 0.f, 0.f, 0.f};
#pragma unroll
    for (int i = 0; i < 4; ++i) {
        const int cot = wv * 4 + i;                  // co-tile 0..15
#pragma unroll
        for (int kh = 0; kh < 2; ++kh) {
            const bf16x8 a = *(const bf16x8*)(wip +
                (size_t)(cot * 16 + n16) * 64 + kh * 32 + quad * 8);
#pragma unroll
            for (int p = 0; p < 2; ++p) {
                const bf16x8 bb = *(const bf16x8*)&ltile[
                    (p * 16 + n16) * 72 + kh * 32 + quad * 8];
                acc[i][p] = __builtin_amdgcn_mfma_f32_16x16x32_bf16(a, bb, acc[i][p], 0, 0, 0);
            }
        }
    }
#pragma unroll
    for (int i = 0; i < 4; ++i) {
        const int cot = wv * 4 + i;
#pragma unroll
        for (int p = 0; p < 2; ++p) {
            const int pos = p * 16 + n16;
#pragma unroll
            for (int r = 0; r < 4; ++r) {
                const int e = cot * 16 + quad * 4 + r;
                const float v = acc[i][p][r];
                if (e < 128) xin_raw[((size_t)(b * 128 + e)) * 4096 + l0 + pos] = v;
                else ztile[pos * 140 + (e - 128)] = v;
            }
        }
    }
    __syncthreads();
    {
        const int pos = t >> 3, d0 = (t & 7) * 16;
        float* dst = z + ((size_t)(b * 4096 + l0 + pos)) * 128 + d0;
        const float* srcz = ztile + pos * 140 + d0;
#pragma unroll
        for (int q = 0; q < 4; ++q)
            *(float4*)(dst + q * 4) = *(const float4*)(srcz + q * 4);
    }
}

// ---------------------------------------------------------------------------
// Depthwise 3x3 SAME conv + bias + SiLU, fused with spatial transpose.
// ---------------------------------------------------------------------------
__global__ __launch_bounds__(256) void dwconv_silu_T_k(const float* __restrict__ in,
    const float* __restrict__ w, const float* __restrict__ bias,
    float* __restrict__ xin_s, float* __restrict__ xin_T)
{
    const int bd = blockIdx.x;                       // b*128 + d
    const int d = bd & 127;
    const int t = threadIdx.x;
    __shared__ float pin[64 * 65], pout[64 * 65];
    const float* src = in + (size_t)bd * 4096;
#pragma unroll
    for (int i = 0; i < 16; ++i) {
        const int e = i * 256 + t;
        pin[(e >> 6) * 65 + (e & 63)] = src[e];
    }
    __syncthreads();
    const float w0 = w[d * 9 + 0], w1 = w[d * 9 + 1], w2 = w[d * 9 + 2];
    const float w3 = w[d * 9 + 3], w4 = w[d * 9 + 4], w5 = w[d * 9 + 5];
    const float w6 = w[d * 9 + 6], w7 = w[d * 9 + 7], w8 = w[d * 9 + 8];
    const float bv = bias[d];
    float* outs = xin_s + (size_t)bd * 4096;
#pragma unroll
    for (int i = 0; i < 16; ++i) {
        const int e = i * 256 + t;
        const int hh = e >> 6, ww = e & 63;
        float acc = bv;
        const bool h0 = hh > 0, h1 = hh < 63, v0 = ww > 0, v1 = ww < 63;
        const float* rm = pin + (hh - 1) * 65;
        const float* rc = pin + hh * 65;
        const float* rp = pin + (hh + 1) * 65;
        if (h0) {
            if (v0) acc = fmaf(rm[ww - 1], w0, acc);
            acc = fmaf(rm[ww], w1, acc);
            if (v1) acc = fmaf(rm[ww + 1], w2, acc);
        }
        if (v0) acc = fmaf(rc[ww - 1], w3, acc);
        acc = fmaf(rc[ww], w4, acc);
        if (v1) acc = fmaf(rc[ww + 1], w5, acc);
        if (h1) {
            if (v0) acc = fmaf(rp[ww - 1], w6, acc);
            acc = fmaf(rp[ww], w7, acc);
            if (v1) acc = fmaf(rp[ww + 1], w8, acc);
        }
        const float val = acc / (1.f + __expf(-acc));
        pout[hh * 65 + ww] = val;
        outs[e] = val;
    }
    __syncthreads();
    float* outT = xin_T + (size_t)bd * 4096;
#pragma unroll
    for (int i = 0; i < 16; ++i) {
        const int e = i * 256 + t;
        const int wi = e >> 6, hi = e & 63;
        outT[e] = pout[hi * 65 + wi];
    }
}

// ---------------------------------------------------------------------------
// x_dbl[b,k,c,m] = sum_d xs[b,k,d,m] * x_proj_w[k,c,d]  (c=36, scan order m).
// ---------------------------------------------------------------------------
__global__ __launch_bounds__(256) void xdbl_k(const float* __restrict__ xin_s,
    const float* __restrict__ xin_T, const float* __restrict__ xpw,
    float* __restrict__ xdbl)
{
    const int bx = blockIdx.x;
    const int bk = bx >> 7, m0 = (bx & 127) * 32;
    const int b = bk >> 2, k = bk & 3;
    __shared__ float tl[32 * 132];   // [j][d], pad 132
    const float* src = (k & 1) ? xin_T : xin_s;
    const bool rev = (k >= 2);
    for (int e = threadIdx.x; e < 4096; e += 256) {
        const int d = e >> 5, j = e & 31;
        const int m = m0 + j;
        const int um = rev ? (4095 - m) : m;
        tl[j * 132 + d] = src[(b * 128 + d) * 4096 + um];
    }
    __syncthreads();
    const int j = threadIdx.x & 31, c0 = threadIdx.x >> 5;
    const float4* xv4 = (const float4*)(tl + j * 132);
    float acc[5] = {0.f, 0.f, 0.f, 0.f, 0.f};
    for (int d4 = 0; d4 < 32; ++d4) {
        const float4 xv = xv4[d4];
#pragma unroll
        for (int q = 0; q < 5; ++q) {
            const int c = c0 + q * 8;
            if (c < 36) {
                const float4 wv = *(const float4*)&xpw[((size_t)(k * 36 + c)) * 128 + d4 * 4];
                acc[q] = fmaf(xv.x, wv.x, acc[q]);
                acc[q] = fmaf(xv.y, wv.y, acc[q]);
                acc[q] = fmaf(xv.z, wv.z, acc[q]);
                acc[q] = fmaf(xv.w, wv.w, acc[q]);
            }
        }
    }
#pragma unroll
    for (int q = 0; q < 5; ++q) {
        const int c = c0 + q * 8;
        if (c < 36) xdbl[((size_t)bk * 36 + c) * 4096 + m0 + j] = acc[q];
    }
}

// ---------------------------------------------------------------------------
// Segmented scan, phase 1. SEG=64 (8192 blocks), 13KB LDS. (R13-verified)
// ---------------------------------------------------------------------------
__global__ __launch_bounds__(256) void scan_p1_k(const float* __restrict__ xdbl,
    const float* __restrict__ xin_s, const float* __restrict__ xin_T,
    const float* __restrict__ A_logs, const float* __restrict__ dtw,
    const float* __restrict__ dtb, float* __restrict__ hseg,
    float* __restrict__ pseg)
{
    const int bx = blockIdx.x;
    const int seg = bx & 63, d8 = (bx >> 6) & 7, bk = bx >> 9;
    const int b = bk >> 2, k = bk & 3;
    const int t = threadIdx.x;
    const int chain = t >> 4, n = t & 15;
    const int d = d8 * 16 + chain;
    const float A = -__expf(A_logs[(k * 128 + d) * 16 + n]);
    __shared__ float sB[16 * 68], sdt[16 * 68], sdu[16 * 68];
    const float* srcu = (k & 1) ? xin_T : xin_s;
    const bool rev = (k >= 2);
    const int col = t & 63, r0 = t >> 6;
    const int m0 = seg * 64;
    {
        const float dts0 = xdbl[((size_t)bk * 36 + 0) * 4096 + m0 + col];
        const float dts1 = xdbl[((size_t)bk * 36 + 1) * 4096 + m0 + col];
        const float dts2 = xdbl[((size_t)bk * 36 + 2) * 4096 + m0 + col];
        const float dts3 = xdbl[((size_t)bk * 36 + 3) * 4096 + m0 + col];
        const int m = m0 + col;
        const int um = rev ? (4095 - m) : m;
#pragma unroll
        for (int i = 0; i < 4; ++i) {
            const int nn = r0 + 4 * i;
            sB[nn * 68 + col] = xdbl[((size_t)bk * 36 + 4 + nn) * 4096 + m0 + col];
            const int dd = d8 * 16 + nn;
            const float* wp = dtw + (k * 128 + dd) * 4;
            float s = dtb[k * 128 + dd];
            s = fmaf(dts0, wp[0], s);
            s = fmaf(dts1, wp[1], s);
            s = fmaf(dts2, wp[2], s);
            s = fmaf(dts3, wp[3], s);
            const float sp = (s > 20.f) ? s : log1pf(__expf(s));
            sdt[nn * 68 + col] = sp;
            sdu[nn * 68 + col] = sp * srcu[(b * 128 + dd) * 4096 + um];
        }
    }
    __syncthreads();
    const float4* B4  = (const float4*)(sB + n * 68);
    const float4* dt4 = (const float4*)(sdt + chain * 68);
    const float4* du4 = (const float4*)(sdu + chain * 68);
    float h = 0.f, pr = 1.f;
#pragma unroll 4
    for (int q = 0; q < 16; ++q) {
        const float4 dt = dt4[q], du = du4[q], BB = B4[q];
        float a;
        a = __expf(dt.x * A); h = fmaf(h, a, du.x * BB.x); pr *= a;
        a = __expf(dt.y * A); h = fmaf(h, a, du.y * BB.y); pr *= a;
        a = __expf(dt.z * A); h = fmaf(h, a, du.z * BB.z); pr *= a;
        a = __expf(dt.w * A); h = fmaf(h, a, du.w * BB.w); pr *= a;
    }
    const size_t idx = (size_t)seg * 32768 + (size_t)(bk * 128 + d) * 16 + n;
    hseg[idx] = h;
    pseg[idx] = pr;
}

// ---------------------------------------------------------------------------
// Combine segment summaries (coalesced), 64 links. pseg -> h_start in place.
// ---------------------------------------------------------------------------
__global__ __launch_bounds__(256) void scan_combine_k(const float* __restrict__ hseg,
                                                      float* __restrict__ pseg)
{
    const int i = blockIdx.x * 256 + threadIdx.x;  // 0..32767
    float h = 0.f;
#pragma unroll 4
    for (int s = 0; s < 64; ++s) {
        const size_t idx = (size_t)s * 32768 + i;
        const float p = pseg[idx];
        const float he = hseg[idx];
        pseg[idx] = h;
        h = fmaf(h, p, he);
    }
}

// ---------------------------------------------------------------------------
// Segmented scan, phase 2. SEG=64 (8192 blocks), 21.25KB LDS, bf16 ybuf
// stored at output l. (R13-verified)
// ---------------------------------------------------------------------------
__global__ __launch_bounds__(256) void scan_p2_k(const float* __restrict__ xdbl,
    const float* __restrict__ xin_s, const float* __restrict__ xin_T,
    const float* __restrict__ A_logs, const float* __restrict__ dtw,
    const float* __restrict__ dtb, const float* __restrict__ hstart,
    const float* __restrict__ Dsp, unsigned short* __restrict__ ybuf)
{
    const int bx = blockIdx.x;
    const int seg = bx & 63, d8 = (bx >> 6) & 7, bk = bx >> 9;
    const int b = bk >> 2, k = bk & 3;
    const int t = threadIdx.x;
    const int chain = t >> 4, n = t & 15;
    const int d = d8 * 16 + chain;
    const float A = -__expf(A_logs[(k * 128 + d) * 16 + n]);
    __shared__ float sB[16 * 68], sC[16 * 68], sdt[16 * 68], su[16 * 68];
    __shared__ float sy[64 * 16];   // [j][dd]
    const float* srcu = (k & 1) ? xin_T : xin_s;
    const bool rev = (k >= 2);
    const int col = t & 63, r0 = t >> 6;
    const int m0 = seg * 64;
    const float Dk0 = (k == 0)
        ? (Dsp[d] + Dsp[128 + d] + Dsp[256 + d] + Dsp[384 + d]) : 0.f;
    float h = hstart[(size_t)seg * 32768 + (size_t)(bk * 128 + d) * 16 + n];
    {
        const float dts0 = xdbl[((size_t)bk * 36 + 0) * 4096 + m0 + col];
        const float dts1 = xdbl[((size_t)bk * 36 + 1) * 4096 + m0 + col];
        const float dts2 = xdbl[((size_t)bk * 36 + 2) * 4096 + m0 + col];
        const float dts3 = xdbl[((size_t)bk * 36 + 3) * 4096 + m0 + col];
        const int m = m0 + col;
        const int um = rev ? (4095 - m) : m;
#pragma unroll
        for (int i = 0; i < 4; ++i) {
            const int nn = r0 + 4 * i;
            sB[nn * 68 + col] = xdbl[((size_t)bk * 36 + 4 + nn) * 4096 + m0 + col];
            sC[nn * 68 + col] = xdbl[((size_t)bk * 36 + 20 + nn) * 4096 + m0 + col];
            const int dd = d8 * 16 + nn;
            const float* wp = dtw + (k * 128 + dd) * 4;
            float s = dtb[k * 128 + dd];
            s = fmaf(dts0, wp[0], s);
            s = fmaf(dts1, wp[1], s);
            s = fmaf(dts2, wp[2], s);
            s = fmaf(dts3, wp[3], s);
            const float sp = (s > 20.f) ? s : log1pf(__expf(s));
            sdt[nn * 68 + col] = sp;
            const float uval = srcu[(b * 128 + dd) * 4096 + um];
            su[nn * 68 + col] = (k == 0) ? uval : sp * uval;   // u or du
        }
    }
    __syncthreads();
    const float4* B4  = (const float4*)(sB + n * 68);
    const float4* C4  = (const float4*)(sC + n * 68);
    const float4* dt4 = (const float4*)(sdt + chain * 68);
    const float4* u4  = (const float4*)(su + chain * 68);
    if (k == 0) {
#pragma unroll 4
        for (int q = 0; q < 16; ++q) {
            const float4 dt = dt4[q], uu = u4[q], BB = B4[q], CC = C4[q];
            float a, p;
#define SCAN_STEP(E, IDX)                                                     \
            a = __expf(dt.E * A);                                             \
            h = fmaf(h, a, dt.E * uu.E * BB.E);                               \
            p = dpp_sum16(h * CC.E);                                          \
            if (n == 0) {                                                     \
                const int jg = q * 4 + IDX;                                   \
                sy[jg * 16 + chain] = fmaf(Dk0, uu.E, p);                     \
            }
            SCAN_STEP(x, 0)
            SCAN_STEP(y, 1)
            SCAN_STEP(z, 2)
            SCAN_STEP(w, 3)
#undef SCAN_STEP
        }
    } else {
#pragma unroll 4
        for (int q = 0; q < 16; ++q) {
            const float4 dt = dt4[q], du = u4[q], BB = B4[q], CC = C4[q];
            float a, p;
#define SCAN_STEP(E, IDX)                                                     \
            a = __expf(dt.E * A);                                             \
            h = fmaf(h, a, du.E * BB.E);                                      \
            p = dpp_sum16(h * CC.E);                                          \
            if (n == 0) {                                                     \
                const int jg = q * 4 + IDX;                                   \
                sy[jg * 16 + chain] = p;                                      \
            }
            SCAN_STEP(x, 0)
            SCAN_STEP(y, 1)
            SCAN_STEP(z, 2)
            SCAN_STEP(w, 3)
#undef SCAN_STEP
        }
    }
    __syncthreads();
    const int ddl = t & 15;
    const int dg = d8 * 16 + ddl;
    unsigned short* yk = ybuf + (size_t)(k * 4 + b) * 4096 * 128;
#pragma unroll
    for (int p2 = 0; p2 < 4; ++p2) {
        const int e = p2 * 256 + t;
        const int j = e >> 4;               // 0..63
        const int m = m0 + j;
        int l;
        if (k == 0) l = m;
        else if (k == 1) l = ((m & 63) << 6) | (m >> 6);
        else if (k == 2) l = 4095 - m;
        else { const int mf = 4095 - m; l = ((mf & 63) << 6) | (mf >> 6); }
        yk[(size_t)l * 128 + dg] = (unsigned short)f2bf(sy[j * 16 + ddl]);
    }
}

// ---------------------------------------------------------------------------
// Finalize: v[d] = sum_k ybuf[k][b][l][d] (bf16); LN over 128; * silu(z);
// out_proj GEMV; LDS-transposed coalesced store + skip*x1. Block = 32 l.
// ---------------------------------------------------------------------------
__global__ __launch_bounds__(256) void finalize_k(const unsigned short* __restrict__ ybuf,
    const float* __restrict__ z, const float* __restrict__ x1,
    const float* __restrict__ ong, const float* __restrict__ onb,
    const float* __restrict__ opw, const float* __restrict__ skipp,
    float* __restrict__ res)
{
    const int bx = blockIdx.x;               // b*128 + tile
    const int b = bx >> 7, l0 = (bx & 127) * 32;
    const int t = threadIdx.x;
    const int j = t & 31, g = t >> 5;        // g 0..7
    const int l = l0 + j;
    const u16x8* y0p = (const u16x8*)(ybuf + ((size_t)(0 + b) * 4096 + l) * 128);
    const u16x8* y1p = (const u16x8*)(ybuf + ((size_t)(4 + b) * 4096 + l) * 128);
    const u16x8* y2p = (const u16x8*)(ybuf + ((size_t)(8 + b) * 4096 + l) * 128);
    const u16x8* y3p = (const u16x8*)(ybuf + ((size_t)(12 + b) * 4096 + l) * 128);
    float vr[128];
    float s1 = 0.f, s2 = 0.f;
#pragma unroll
    for (int g8 = 0; g8 < 16; ++g8) {
        const u16x8 a0 = y0p[g8], a1 = y1p[g8], a2 = y2p[g8], a3 = y3p[g8];
#pragma unroll
        for (int e = 0; e < 8; ++e) {
            const float f = (b2f(a0[e]) + b2f(a1[e])) + (b2f(a2[e]) + b2f(a3[e]));
            vr[g8 * 8 + e] = f;
            s1 += f; s2 = fmaf(f, f, s2);
        }
    }
    const float mu = s1 * (1.f / 128.f);
    const float var = s2 * (1.f / 128.f) - mu * mu;
    const float rstd = rsqrtf(var + 1e-5f);
    const float4* zp = (const float4*)(z + ((size_t)(b * 4096 + l)) * 128);
    const float4* gp = (const float4*)ong;
    const float4* bp = (const float4*)onb;
#pragma unroll
    for (int d4 = 0; d4 < 32; ++d4) {
        const float4 gg = gp[d4], bb = bp[d4], zz = zp[d4];
#define GATE(E, IDX)                                                          \
        {                                                                     \
            const float yln = (vr[d4 * 4 + IDX] - mu) * rstd * gg.E + bb.E;   \
            vr[d4 * 4 + IDX] = yln * (zz.E / (1.f + __expf(-zz.E)));          \
        }
        GATE(x, 0) GATE(y, 1) GATE(z, 2) GATE(w, 3)
#undef GATE
    }
    float acc[8] = {0.f, 0.f, 0.f, 0.f, 0.f, 0.f, 0.f, 0.f};
    for (int d4 = 0; d4 < 32; ++d4) {
#pragma unroll
        for (int q = 0; q < 8; ++q) {
            const float4 wv = *(const float4*)&opw[(size_t)(g * 8 + q) * 128 + d4 * 4];
            acc[q] = fmaf(vr[d4 * 4 + 0], wv.x, acc[q]);
            acc[q] = fmaf(vr[d4 * 4 + 1], wv.y, acc[q]);
            acc[q] = fmaf(vr[d4 * 4 + 2], wv.z, acc[q]);
            acc[q] = fmaf(vr[d4 * 4 + 3], wv.w, acc[q]);
        }
    }
    __shared__ float sres[64 * 33];
#pragma unroll
    for (int q = 0; q < 8; ++q) sres[(g * 8 + q) * 33 + j] = acc[q];
    __syncthreads();
    const float sk = skipp[0];
    for (int e = t; e < 2048; e += 256) {
        const int co = e >> 5, jj = e & 31;
        const size_t o = ((size_t)(b * 64 + co)) * 4096 + l0 + jj;
        res[o] = sres[co * 33 + jj] + sk * x1[o];
    }
}

// ---------------------------------------------------------------------------
// Workspace layout (floats), ~77.4 MB:
//   x1 @0 (1M), xin_s @1M (2M), zbuf @3M (2M), xin_T @5M (2M),
//   xdbl @7,340,032 (2,359,296), ybuf @9,699,328 (bf16, 4M float-slots),
//   hseg @13,893,632 (2M), pseg @15,990,784 (2M),
//   G @18,087,936 (2M): conv chain / xin_raw / res+tmp,
//   wbf @20,185,088 (81,920),
//   stats @20,267,008 (1024: conv1 s1/s2 @0/256, cb s1/s2 @512/768)
// ---------------------------------------------------------------------------
extern "C" void kernel_launch(void* const* d_in, const int* in_sizes, int n_in,
                              void* d_out, int out_size, void* d_ws, size_t ws_size,
                              hipStream_t stream)
{
    const float* x          = (const float*)d_in[0];
    const float* conv1_w    = (const float*)d_in[1];
    const float* conv1_b    = (const float*)d_in[2];
    const float* conv2_w    = (const float*)d_in[3];
    const float* conv2_b    = (const float*)d_in[4];
    const float* cf_w       = (const float*)d_in[5];
    const float* cf_b       = (const float*)d_in[6];
    const float* ln_g       = (const float*)d_in[7];
    const float* ln_b       = (const float*)d_in[8];
    const float* in_proj_w  = (const float*)d_in[9];
    const float* dw_w       = (const float*)d_in[10];
    const float* dw_b       = (const float*)d_in[11];
    const float* x_proj_w   = (const float*)d_in[12];
    const float* dt_proj_w  = (const float*)d_in[13];
    const float* dt_proj_b  = (const float*)d_in[14];
    const float* A_logs     = (const float*)d_in[15];
    const float* Ds         = (const float*)d_in[16];
    const float* out_norm_g = (const float*)d_in[17];
    const float* out_norm_b = (const float*)d_in[18];
    const float* out_proj_w = (const float*)d_in[19];
    const float* skip_scale = (const float*)d_in[20];
    const float* cb_w       = (const float*)d_in[21];
    const float* cb_b       = (const float*)d_in[22];

    float* ws = (float*)d_ws;
    float* x1    = ws;                 // 1,048,576
    float* xin_s = ws + 1048576;       // 2,097,152
    float* zbuf  = ws + 3145728;       // 2,097,152
    float* xin_T = ws + 5242880;       // 2,097,152
    float* xdbl  = ws + 7340032;       // 2,359,296
    unsigned short* ybuf = (unsigned short*)(ws + 9699328);  // bf16 [k][b][l][d]
    float* hseg  = ws + 13893632;      // 2,097,152
    float* pseg  = ws + 15990784;      // 2,097,152
    float* G     = ws + 18087936;      // 2,097,152 scratch
    float* G0 = G;
    float* G1 = G + 1048576;
    short* wbf  = (short*)(ws + 20185088);  // 163,840 bf16
    short* wbf1 = wbf;
    short* wbf2 = wbf + 36864;
    short* wbf3 = wbf + 73728;
    short* wbf4 = wbf + 110592;
    short* wip  = wbf + 147456;
    float* stats1 = ws + 20267008;           // 512 (conv1 out stats)
    float* stats2 = ws + 20267520;           // 512 (cb out stats)

    hipMemsetAsync(stats1, 0, 1024 * sizeof(float), stream);

    wconv_k<<<640, 256, 0, stream>>>(conv1_w, conv2_w, cf_w, cb_w, in_proj_w, wbf);

    conv3x3_mfma_k<<<256, 256, 0, stream>>>(x, wbf1, conv1_b, nullptr,
                                            nullptr, stats1, G0);
    conv3x3_mfma_k<<<256, 256, 0, stream>>>(G0, wbf2, conv2_b, nullptr,
                                            stats1, nullptr, G1);
    conv3x3_mfma_k<<<256, 256, 0, stream>>>(G1, wbf3, cf_b, nullptr,
                                            nullptr, nullptr, x1);
    ln_inproj_mfma_k<<<512, 256, 0, stream>>>(x1, ln_g, ln_b, wip, G /*xin_raw*/, zbuf);
    dwconv_silu_T_k<<<512, 256, 0, stream>>>(G /*xin_raw*/, dw_w, dw_b, xin_s, xin_T);
    xdbl_k<<<2048, 256, 0, stream>>>(xin_s, xin_T, x_proj_w, xdbl);
    scan_p1_k<<<8192, 256, 0, stream>>>(xdbl, xin_s, xin_T, A_logs, dt_proj_w,
                                        dt_proj_b, hseg, pseg);
    scan_combine_k<<<128, 256, 0, stream>>>(hseg, pseg /*-> hstart*/);
    scan_p2_k<<<8192, 256, 0, stream>>>(xdbl, xin_s, xin_T, A_logs, dt_proj_w,
                                        dt_proj_b, pseg /*hstart*/, Ds, ybuf);
    finalize_k<<<512, 256, 0, stream>>>(ybuf, zbuf, x1, out_norm_g, out_norm_b,
                                        out_proj_w, skip_scale, G0 /*res*/);
    conv3x3_mfma_k<<<256, 256, 0, stream>>>(G0 /*res*/, wbf4, cb_b, x1,
                                            nullptr, stats2, G1 /*tmp*/);
    inorm_apply_k<<<256, 256, 0, stream>>>(G1 /*tmp*/, stats2, (float*)d_out);
}

// Round 16
// 383.159 us; speedup vs baseline: 3.0601x; 1.0098x over previous
//
#include <hip/hip_runtime.h>
#include <hip/hip_bf16.h>

// All inputs/outputs are float32 (per the reference file's setup_inputs).

typedef __attribute__((ext_vector_type(8))) short bf16x8;
typedef __attribute__((ext_vector_type(8))) unsigned short u16x8;
typedef __attribute__((ext_vector_type(4))) float f32x4;
typedef unsigned short u16;

static __device__ __forceinline__ short f2bf(float f)
{
    unsigned u = __float_as_uint(f);
    unsigned r = u + 0x7FFFu + ((u >> 16) & 1u);   // RNE
    return (short)(r >> 16);
}
static __device__ __forceinline__ float b2f(u16 s)
{
    return __uint_as_float((unsigned)s << 16);
}

// 16-lane butterfly sum via DPP (VALU, no DS-pipe traffic).
static __device__ __forceinline__ float dpp_sum16(float x)
{
    x += __int_as_float(__builtin_amdgcn_update_dpp(
        0, __float_as_int(x), 0xB1, 0xF, 0xF, true));   // quad_perm [1,0,3,2]
    x += __int_as_float(__builtin_amdgcn_update_dpp(
        0, __float_as_int(x), 0x4E, 0xF, 0xF, true));   // quad_perm [2,3,0,1]
    x += __int_as_float(__builtin_amdgcn_update_dpp(
        0, __float_as_int(x), 0x141, 0xF, 0xF, true));  // row_half_mirror
    x += __int_as_float(__builtin_amdgcn_update_dpp(
        0, __float_as_int(x), 0x140, 0xF, 0xF, true));  // row_mirror
    return x;
}

// ---------------------------------------------------------------------------
// Weight conversion (4 convs + in_proj -> bf16).
// ---------------------------------------------------------------------------
__global__ __launch_bounds__(256) void wconv_k(const float* __restrict__ w1,
    const float* __restrict__ w2, const float* __restrict__ w3,
    const float* __restrict__ w4, const float* __restrict__ ipw,
    short* __restrict__ wbf)
{
    const int idx = blockIdx.x * 256 + threadIdx.x;  // 0..163839
    if (idx < 147456) {
        const int c = idx / 36864, rem = idx % 36864;
        const int tap = rem >> 12, r2 = rem & 4095;
        const int co = r2 >> 6, ci = r2 & 63;
        const float* src = (c == 0) ? w1 : (c == 1) ? w2 : (c == 2) ? w3 : w4;
        wbf[idx] = f2bf(src[(co * 64 + ci) * 9 + tap]);
    } else {
        const int i2 = idx - 147456;                 // [e][c]
        wbf[idx] = f2bf(ipw[i2]);
    }
}

// ---------------------------------------------------------------------------
// MFMA 3x3 SAME conv, 64->64 ch, NCHW. Block = one (b,h) row, 256 threads.
// instats: apply InstanceNorm+LeakyReLU to input during staging.
// outstats: epilogue accumulates per-(b,co) sum/sumsq (DPP + atomicAdd).
// ---------------------------------------------------------------------------
__global__ __launch_bounds__(256) void conv3x3_mfma_k(const float* __restrict__ in,
    const short* __restrict__ wtap, const float* __restrict__ bias,
    const float* __restrict__ addsrc, const float* __restrict__ instats,
    float* __restrict__ outstats, float* __restrict__ out)
{
    const int bh = blockIdx.x;
    const int b = bh >> 6, h = bh & 63;
    const int t = threadIdx.x;
    __shared__ __align__(16) short lin[3 * 66 * 72];  // [r][w+1][ci]
    {
        const int ci = t >> 2, w16 = (t & 3) * 16;
        float mu = 0.f, rstd = 1.f;
        if (instats) {
            const float S1 = instats[(b << 6) + ci];
            const float S2 = instats[256 + (b << 6) + ci];
            mu = S1 * (1.f / 4096.f);
            rstd = rsqrtf(S2 * (1.f / 4096.f) - mu * mu + 1e-5f);
        }
#pragma unroll
        for (int r = 0; r < 3; ++r) {
            const int hh = h - 1 + r;
            const bool ok = (hh >= 0 && hh < 64);
            const float* src = in + ((size_t)(b * 64 + ci) * 64 + (ok ? hh : 0)) * 64 + w16;
#pragma unroll
            for (int q = 0; q < 4; ++q) {
                float4 v = make_float4(0.f, 0.f, 0.f, 0.f);
                if (ok) {
                    v = *(const float4*)(src + q * 4);
                    if (instats) {
#define NRM(E) { float nv = (v.E - mu) * rstd; v.E = (nv >= 0.f) ? nv : 0.2f * nv; }
                        NRM(x) NRM(y) NRM(z) NRM(w)
#undef NRM
                    }
                }
                const int wb = w16 + q * 4;
                lin[(r * 66 + wb + 1) * 72 + ci] = f2bf(v.x);
                lin[(r * 66 + wb + 2) * 72 + ci] = f2bf(v.y);
                lin[(r * 66 + wb + 3) * 72 + ci] = f2bf(v.z);
                lin[(r * 66 + wb + 4) * 72 + ci] = f2bf(v.w);
            }
        }
        if (t < 216) {
            const int r3 = t / 72, rem = t % 72;
            const int colp = (rem >= 36) ? 65 : 0, ci2 = rem % 36;
            ((int*)lin)[(r3 * 66 + colp) * 36 + ci2] = 0;
        }
    }
    __syncthreads();
    const int lane = t & 63, ct = t >> 6;     // wave = co-tile
    const int n16 = lane & 15, quad = lane >> 4;
    f32x4 acc0 = {0.f, 0.f, 0.f, 0.f};
    f32x4 acc1 = {0.f, 0.f, 0.f, 0.f};
    f32x4 acc2 = {0.f, 0.f, 0.f, 0.f};
    f32x4 acc3 = {0.f, 0.f, 0.f, 0.f};
#pragma unroll
    for (int tap = 0; tap < 9; ++tap) {
        const int dy = tap / 3, dx = tap % 3;
#pragma unroll
        for (int kh = 0; kh < 2; ++kh) {
            const int kk = kh * 32;
            const bf16x8 a = *(const bf16x8*)(wtap +
                ((size_t)tap * 64 + ct * 16 + n16) * 64 + kk + quad * 8);
            const int rb = (dy * 66 + n16 + dx) * 72 + kk + quad * 8;
            const bf16x8 b0 = *(const bf16x8*)&lin[rb + 0 * 16 * 72];
            const bf16x8 b1 = *(const bf16x8*)&lin[rb + 1 * 16 * 72];
            const bf16x8 b2 = *(const bf16x8*)&lin[rb + 2 * 16 * 72];
            const bf16x8 b3 = *(const bf16x8*)&lin[rb + 3 * 16 * 72];
            acc0 = __builtin_amdgcn_mfma_f32_16x16x32_bf16(a, b0, acc0, 0, 0, 0);
            acc1 = __builtin_amdgcn_mfma_f32_16x16x32_bf16(a, b1, acc1, 0, 0, 0);
            acc2 = __builtin_amdgcn_mfma_f32_16x16x32_bf16(a, b2, acc2, 0, 0, 0);
            acc3 = __builtin_amdgcn_mfma_f32_16x16x32_bf16(a, b3, acc3, 0, 0, 0);
        }
    }
#pragma unroll
    for (int r = 0; r < 4; ++r) {
        const int co = ct * 16 + quad * 4 + r;
        const float bv = bias[co];
        float* orow = out + ((size_t)(b * 64 + co) * 64 + h) * 64;
        float v0 = acc0[r] + bv, v1 = acc1[r] + bv, v2 = acc2[r] + bv, v3 = acc3[r] + bv;
        if (addsrc) {
            const float* arow = addsrc + ((size_t)(b * 64 + co) * 64 + h) * 64;
            v0 += arow[n16]; v1 += arow[16 + n16];
            v2 += arow[32 + n16]; v3 += arow[48 + n16];
        }
        if (outstats) {
            float ss = (v0 + v1) + (v2 + v3);
            float qq = fmaf(v0, v0, fmaf(v1, v1, fmaf(v2, v2, v3 * v3)));
            ss = dpp_sum16(ss);
            qq = dpp_sum16(qq);
            if (n16 == 0) {
                atomicAdd(&outstats[(b << 6) + co], ss);
                atomicAdd(&outstats[256 + (b << 6) + co], qq);
            }
        }
        orow[n16] = v0; orow[16 + n16] = v1;
        orow[32 + n16] = v2; orow[48 + n16] = v3;
    }
}

// ---------------------------------------------------------------------------
// Final InstanceNorm apply (stats precomputed in cb's epilogue) + LeakyReLU.
// ---------------------------------------------------------------------------
__global__ __launch_bounds__(256) void inorm_apply_k(const float* __restrict__ in,
    const float* __restrict__ stats, float* __restrict__ out)
{
    const int bc = blockIdx.x;
    const float S1 = stats[bc], S2 = stats[256 + bc];
    const float mu = S1 * (1.f / 4096.f);
    const float rstd = rsqrtf(S2 * (1.f / 4096.f) - mu * mu + 1e-5f);
    const float* row = in + (size_t)bc * 4096;
    float* orow = out + (size_t)bc * 4096;
    for (int i = threadIdx.x; i < 4096; i += 256) {
        float v = (row[i] - mu) * rstd;
        orow[i] = (v >= 0.f) ? v : 0.2f * v;
    }
}

// ---------------------------------------------------------------------------
// LayerNorm over 64 ch + in_proj (256x64) via MFMA. Block = 32 positions.
// R16: xin_raw written as bf16 (halves the xin_raw round-trip).
// ---------------------------------------------------------------------------
__global__ __launch_bounds__(256) void ln_inproj_mfma_k(const float* __restrict__ x1,
    const float* __restrict__ g, const float* __restrict__ be,
    const short* __restrict__ wip, u16* __restrict__ xin_raw,
    float* __restrict__ z)
{
    const int bx = blockIdx.x;
    const int b = bx >> 7, l0 = (bx & 127) * 32;
    const int t = threadIdx.x;
    __shared__ __align__(16) short ltile[32 * 72];   // [pos][c]
    __shared__ float ztile[32 * 140];                // [pos][d], pad 140
    {
        const int j = t & 31, gg = t >> 5;           // pos, c-group
        float xr[64];
        float s1 = 0.f, s2 = 0.f;
#pragma unroll
        for (int c = 0; c < 64; ++c) {
            const float v = x1[(b * 64 + c) * 4096 + l0 + j];
            xr[c] = v; s1 += v; s2 = fmaf(v, v, s2);
        }
        const float mu = s1 * (1.f / 64.f);
        const float var = s2 * (1.f / 64.f) - mu * mu;
        const float rstd = rsqrtf(var + 1e-5f);
#pragma unroll
        for (int i = 0; i < 8; ++i) {
            const int c = gg * 8 + i;
            ltile[j * 72 + c] = f2bf((xr[c] - mu) * rstd * g[c] + be[c]);
        }
    }
    __syncthreads();
    const int lane = t & 63, wv = t >> 6;
    const int n16 = lane & 15, quad = lane >> 4;
    f32x4 acc[4][2];
#pragma unroll
    for (int i = 0; i < 4; ++i)
#pragma unroll
        for (int p = 0; p < 2; ++p) acc[i][p] = (f32x4){0.f, 0.f, 0.f, 0.f};
#pragma unroll
    for (int i = 0; i < 4; ++i) {
        const int cot = wv * 4 + i;                  // co-tile 0..15
#pragma unroll
        for (int kh = 0; kh < 2; ++kh) {
            const bf16x8 a = *(const bf16x8*)(wip +
                (size_t)(cot * 16 + n16) * 64 + kh * 32 + quad * 8);
#pragma unroll
            for (int p = 0; p < 2; ++p) {
                const bf16x8 bb = *(const bf16x8*)&ltile[
                    (p * 16 + n16) * 72 + kh * 32 + quad * 8];
                acc[i][p] = __builtin_amdgcn_mfma_f32_16x16x32_bf16(a, bb, acc[i][p], 0, 0, 0);
            }
        }
    }
#pragma unroll
    for (int i = 0; i < 4; ++i) {
        const int cot = wv * 4 + i;
#pragma unroll
        for (int p = 0; p < 2; ++p) {
            const int pos = p * 16 + n16;
#pragma unroll
            for (int r = 0; r < 4; ++r) {
                const int e = cot * 16 + quad * 4 + r;
                const float v = acc[i][p][r];
                if (e < 128) xin_raw[((size_t)(b * 128 + e)) * 4096 + l0 + pos] = (u16)f2bf(v);
                else ztile[pos * 140 + (e - 128)] = v;
            }
        }
    }
    __syncthreads();
    {
        const int pos = t >> 3, d0 = (t & 7) * 16;
        float* dst = z + ((size_t)(b * 4096 + l0 + pos)) * 128 + d0;
        const float* srcz = ztile + pos * 140 + d0;
#pragma unroll
        for (int q = 0; q < 4; ++q)
            *(float4*)(dst + q * 4) = *(const float4*)(srcz + q * 4);
    }
}

// ---------------------------------------------------------------------------
// Depthwise 3x3 SAME conv + bias + SiLU, fused with spatial transpose.
// R16: bf16 in (xin_raw) and bf16 out (xin_s, xin_T) — halves all traffic.
// ---------------------------------------------------------------------------
__global__ __launch_bounds__(256) void dwconv_silu_T_k(const u16* __restrict__ in,
    const float* __restrict__ w, const float* __restrict__ bias,
    u16* __restrict__ xin_s, u16* __restrict__ xin_T)
{
    const int bd = blockIdx.x;                       // b*128 + d
    const int d = bd & 127;
    const int t = threadIdx.x;
    __shared__ float pin[64 * 65];
    __shared__ u16 pout[64 * 65];
    const u16* src = in + (size_t)bd * 4096;
#pragma unroll
    for (int i = 0; i < 16; ++i) {
        const int e = i * 256 + t;
        pin[(e >> 6) * 65 + (e & 63)] = b2f(src[e]);
    }
    __syncthreads();
    const float w0 = w[d * 9 + 0], w1 = w[d * 9 + 1], w2 = w[d * 9 + 2];
    const float w3 = w[d * 9 + 3], w4 = w[d * 9 + 4], w5 = w[d * 9 + 5];
    const float w6 = w[d * 9 + 6], w7 = w[d * 9 + 7], w8 = w[d * 9 + 8];
    const float bv = bias[d];
    u16* outs = xin_s + (size_t)bd * 4096;
#pragma unroll
    for (int i = 0; i < 16; ++i) {
        const int e = i * 256 + t;
        const int hh = e >> 6, ww = e & 63;
        float acc = bv;
        const bool h0 = hh > 0, h1 = hh < 63, v0 = ww > 0, v1 = ww < 63;
        const float* rm = pin + (hh - 1) * 65;
        const float* rc = pin + hh * 65;
        const float* rp = pin + (hh + 1) * 65;
        if (h0) {
            if (v0) acc = fmaf(rm[ww - 1], w0, acc);
            acc = fmaf(rm[ww], w1, acc);
            if (v1) acc = fmaf(rm[ww + 1], w2, acc);
        }
        if (v0) acc = fmaf(rc[ww - 1], w3, acc);
        acc = fmaf(rc[ww], w4, acc);
        if (v1) acc = fmaf(rc[ww + 1], w5, acc);
        if (h1) {
            if (v0) acc = fmaf(rp[ww - 1], w6, acc);
            acc = fmaf(rp[ww], w7, acc);
            if (v1) acc = fmaf(rp[ww + 1], w8, acc);
        }
        const float val = acc / (1.f + __expf(-acc));
        const u16 bf = (u16)f2bf(val);
        pout[hh * 65 + ww] = bf;
        outs[e] = bf;
    }
    __syncthreads();
    u16* outT = xin_T + (size_t)bd * 4096;
#pragma unroll
    for (int i = 0; i < 16; ++i) {
        const int e = i * 256 + t;
        const int wi = e >> 6, hi = e & 63;
        outT[e] = pout[hi * 65 + wi];
    }
}

// ---------------------------------------------------------------------------
// x_dbl[b,k,c,m] = sum_d xs[b,k,d,m] * x_proj_w[k,c,d]  (c=36, scan order m).
// R16: bf16 u inputs (convert at staging; fp32 math unchanged).
// ---------------------------------------------------------------------------
__global__ __launch_bounds__(256) void xdbl_k(const u16* __restrict__ xin_s,
    const u16* __restrict__ xin_T, const float* __restrict__ xpw,
    float* __restrict__ xdbl)
{
    const int bx = blockIdx.x;
    const int bk = bx >> 7, m0 = (bx & 127) * 32;
    const int b = bk >> 2, k = bk & 3;
    __shared__ float tl[32 * 132];   // [j][d], pad 132
    const u16* src = (k & 1) ? xin_T : xin_s;
    const bool rev = (k >= 2);
    for (int e = threadIdx.x; e < 4096; e += 256) {
        const int d = e >> 5, j = e & 31;
        const int m = m0 + j;
        const int um = rev ? (4095 - m) : m;
        tl[j * 132 + d] = b2f(src[(size_t)(b * 128 + d) * 4096 + um]);
    }
    __syncthreads();
    const int j = threadIdx.x & 31, c0 = threadIdx.x >> 5;
    const float4* xv4 = (const float4*)(tl + j * 132);
    float acc[5] = {0.f, 0.f, 0.f, 0.f, 0.f};
    for (int d4 = 0; d4 < 32; ++d4) {
        const float4 xv = xv4[d4];
#pragma unroll
        for (int q = 0; q < 5; ++q) {
            const int c = c0 + q * 8;
            if (c < 36) {
                const float4 wv = *(const float4*)&xpw[((size_t)(k * 36 + c)) * 128 + d4 * 4];
                acc[q] = fmaf(xv.x, wv.x, acc[q]);
                acc[q] = fmaf(xv.y, wv.y, acc[q]);
                acc[q] = fmaf(xv.z, wv.z, acc[q]);
                acc[q] = fmaf(xv.w, wv.w, acc[q]);
            }
        }
    }
#pragma unroll
    for (int q = 0; q < 5; ++q) {
        const int c = c0 + q * 8;
        if (c < 36) xdbl[((size_t)bk * 36 + c) * 4096 + m0 + j] = acc[q];
    }
}

// ---------------------------------------------------------------------------
// Segmented scan, phase 1. SEG=64 (8192 blocks), 13KB LDS. bf16 u reads.
// ---------------------------------------------------------------------------
__global__ __launch_bounds__(256) void scan_p1_k(const float* __restrict__ xdbl,
    const u16* __restrict__ xin_s, const u16* __restrict__ xin_T,
    const float* __restrict__ A_logs, const float* __restrict__ dtw,
    const float* __restrict__ dtb, float* __restrict__ hseg,
    float* __restrict__ pseg)
{
    const int bx = blockIdx.x;
    const int seg = bx & 63, d8 = (bx >> 6) & 7, bk = bx >> 9;
    const int b = bk >> 2, k = bk & 3;
    const int t = threadIdx.x;
    const int chain = t >> 4, n = t & 15;
    const int d = d8 * 16 + chain;
    const float A = -__expf(A_logs[(k * 128 + d) * 16 + n]);
    __shared__ float sB[16 * 68], sdt[16 * 68], sdu[16 * 68];
    const u16* srcu = (k & 1) ? xin_T : xin_s;
    const bool rev = (k >= 2);
    const int col = t & 63, r0 = t >> 6;
    const int m0 = seg * 64;
    {
        const float dts0 = xdbl[((size_t)bk * 36 + 0) * 4096 + m0 + col];
        const float dts1 = xdbl[((size_t)bk * 36 + 1) * 4096 + m0 + col];
        const float dts2 = xdbl[((size_t)bk * 36 + 2) * 4096 + m0 + col];
        const float dts3 = xdbl[((size_t)bk * 36 + 3) * 4096 + m0 + col];
        const int m = m0 + col;
        const int um = rev ? (4095 - m) : m;
#pragma unroll
        for (int i = 0; i < 4; ++i) {
            const int nn = r0 + 4 * i;
            sB[nn * 68 + col] = xdbl[((size_t)bk * 36 + 4 + nn) * 4096 + m0 + col];
            const int dd = d8 * 16 + nn;
            const float* wp = dtw + (k * 128 + dd) * 4;
            float s = dtb[k * 128 + dd];
            s = fmaf(dts0, wp[0], s);
            s = fmaf(dts1, wp[1], s);
            s = fmaf(dts2, wp[2], s);
            s = fmaf(dts3, wp[3], s);
            const float sp = (s > 20.f) ? s : log1pf(__expf(s));
            sdt[nn * 68 + col] = sp;
            sdu[nn * 68 + col] = sp * b2f(srcu[(size_t)(b * 128 + dd) * 4096 + um]);
        }
    }
    __syncthreads();
    const float4* B4  = (const float4*)(sB + n * 68);
    const float4* dt4 = (const float4*)(sdt + chain * 68);
    const float4* du4 = (const float4*)(sdu + chain * 68);
    float h = 0.f, pr = 1.f;
#pragma unroll 4
    for (int q = 0; q < 16; ++q) {
        const float4 dt = dt4[q], du = du4[q], BB = B4[q];
        float a;
        a = __expf(dt.x * A); h = fmaf(h, a, du.x * BB.x); pr *= a;
        a = __expf(dt.y * A); h = fmaf(h, a, du.y * BB.y); pr *= a;
        a = __expf(dt.z * A); h = fmaf(h, a, du.z * BB.z); pr *= a;
        a = __expf(dt.w * A); h = fmaf(h, a, du.w * BB.w); pr *= a;
    }
    const size_t idx = (size_t)seg * 32768 + (size_t)(bk * 128 + d) * 16 + n;
    hseg[idx] = h;
    pseg[idx] = pr;
}

// ---------------------------------------------------------------------------
// Combine segment summaries (coalesced), 64 links. pseg -> h_start in place.
// ---------------------------------------------------------------------------
__global__ __launch_bounds__(256) void scan_combine_k(const float* __restrict__ hseg,
                                                      float* __restrict__ pseg)
{
    const int i = blockIdx.x * 256 + threadIdx.x;  // 0..32767
    float h = 0.f;
#pragma unroll 4
    for (int s = 0; s < 64; ++s) {
        const size_t idx = (size_t)s * 32768 + i;
        const float p = pseg[idx];
        const float he = hseg[idx];
        pseg[idx] = h;
        h = fmaf(h, p, he);
    }
}

// ---------------------------------------------------------------------------
// Segmented scan, phase 2. SEG=64 (8192 blocks), 21.25KB LDS, bf16 u reads,
// bf16 ybuf stored at output l. No atomics.
// ---------------------------------------------------------------------------
__global__ __launch_bounds__(256) void scan_p2_k(const float* __restrict__ xdbl,
    const u16* __restrict__ xin_s, const u16* __restrict__ xin_T,
    const float* __restrict__ A_logs, const float* __restrict__ dtw,
    const float* __restrict__ dtb, const float* __restrict__ hstart,
    const float* __restrict__ Dsp, u16* __restrict__ ybuf)
{
    const int bx = blockIdx.x;
    const int seg = bx & 63, d8 = (bx >> 6) & 7, bk = bx >> 9;
    const int b = bk >> 2, k = bk & 3;
    const int t = threadIdx.x;
    const int chain = t >> 4, n = t & 15;
    const int d = d8 * 16 + chain;
    const float A = -__expf(A_logs[(k * 128 + d) * 16 + n]);
    __shared__ float sB[16 * 68], sC[16 * 68], sdt[16 * 68], su[16 * 68];
    __shared__ float sy[64 * 16];   // [j][dd]
    const u16* srcu = (k & 1) ? xin_T : xin_s;
    const bool rev = (k >= 2);
    const int col = t & 63, r0 = t >> 6;
    const int m0 = seg * 64;
    const float Dk0 = (k == 0)
        ? (Dsp[d] + Dsp[128 + d] + Dsp[256 + d] + Dsp[384 + d]) : 0.f;
    float h = hstart[(size_t)seg * 32768 + (size_t)(bk * 128 + d) * 16 + n];
    {
        const float dts0 = xdbl[((size_t)bk * 36 + 0) * 4096 + m0 + col];
        const float dts1 = xdbl[((size_t)bk * 36 + 1) * 4096 + m0 + col];
        const float dts2 = xdbl[((size_t)bk * 36 + 2) * 4096 + m0 + col];
        const float dts3 = xdbl[((size_t)bk * 36 + 3) * 4096 + m0 + col];
        const int m = m0 + col;
        const int um = rev ? (4095 - m) : m;
#pragma unroll
        for (int i = 0; i < 4; ++i) {
            const int nn = r0 + 4 * i;
            sB[nn * 68 + col] = xdbl[((size_t)bk * 36 + 4 + nn) * 4096 + m0 + col];
            sC[nn * 68 + col] = xdbl[((size_t)bk * 36 + 20 + nn) * 4096 + m0 + col];
            const int dd = d8 * 16 + nn;
            const float* wp = dtw + (k * 128 + dd) * 4;
            float s = dtb[k * 128 + dd];
            s = fmaf(dts0, wp[0], s);
            s = fmaf(dts1, wp[1], s);
            s = fmaf(dts2, wp[2], s);
            s = fmaf(dts3, wp[3], s);
            const float sp = (s > 20.f) ? s : log1pf(__expf(s));
            sdt[nn * 68 + col] = sp;
            const float uval = b2f(srcu[(size_t)(b * 128 + dd) * 4096 + um]);
            su[nn * 68 + col] = (k == 0) ? uval : sp * uval;   // u or du
        }
    }
    __syncthreads();
    const float4* B4  = (const float4*)(sB + n * 68);
    const float4* C4  = (const float4*)(sC + n * 68);
    const float4* dt4 = (const float4*)(sdt + chain * 68);
    const float4* u4  = (const float4*)(su + chain * 68);
    if (k == 0) {
#pragma unroll 4
        for (int q = 0; q < 16; ++q) {
            const float4 dt = dt4[q], uu = u4[q], BB = B4[q], CC = C4[q];
            float a, p;
#define SCAN_STEP(E, IDX)                                                     \
            a = __expf(dt.E * A);                                             \
            h = fmaf(h, a, dt.E * uu.E * BB.E);                               \
            p = dpp_sum16(h * CC.E);                                          \
            if (n == 0) {                                                     \
                const int jg = q * 4 + IDX;                                   \
                sy[jg * 16 + chain] = fmaf(Dk0, uu.E, p);                     \
            }
            SCAN_STEP(x, 0)
            SCAN_STEP(y, 1)
            SCAN_STEP(z, 2)
            SCAN_STEP(w, 3)
#undef SCAN_STEP
        }
    } else {
#pragma unroll 4
        for (int q = 0; q < 16; ++q) {
            const float4 dt = dt4[q], du = u4[q], BB = B4[q], CC = C4[q];
            float a, p;
#define SCAN_STEP(E, IDX)                                                     \
            a = __expf(dt.E * A);                                             \
            h = fmaf(h, a, du.E * BB.E);                                      \
            p = dpp_sum16(h * CC.E);                                          \
            if (n == 0) {                                                     \
                const int jg = q * 4 + IDX;                                   \
                sy[jg * 16 + chain] = p;                                      \
            }
            SCAN_STEP(x, 0)
            SCAN_STEP(y, 1)
            SCAN_STEP(z, 2)
            SCAN_STEP(w, 3)
#undef SCAN_STEP
        }
    }
    __syncthreads();
    const int ddl = t & 15;
    const int dg = d8 * 16 + ddl;
    u16* yk = ybuf + (size_t)(k * 4 + b) * 4096 * 128;
#pragma unroll
    for (int p2 = 0; p2 < 4; ++p2) {
        const int e = p2 * 256 + t;
        const int j = e >> 4;               // 0..63
        const int m = m0 + j;
        int l;
        if (k == 0) l = m;
        else if (k == 1) l = ((m & 63) << 6) | (m >> 6);
        else if (k == 2) l = 4095 - m;
        else { const int mf = 4095 - m; l = ((mf & 63) << 6) | (mf >> 6); }
        yk[(size_t)l * 128 + dg] = (u16)f2bf(sy[j * 16 + ddl]);
    }
}

// ---------------------------------------------------------------------------
// Finalize: v[d] = sum_k ybuf[k][b][l][d] (bf16); LN over 128; * silu(z);
// out_proj GEMV; LDS-transposed coalesced store + skip*x1. Block = 32 l.
// ---------------------------------------------------------------------------
__global__ __launch_bounds__(256) void finalize_k(const u16* __restrict__ ybuf,
    const float* __restrict__ z, const float* __restrict__ x1,
    const float* __restrict__ ong, const float* __restrict__ onb,
    const float* __restrict__ opw, const float* __restrict__ skipp,
    float* __restrict__ res)
{
    const int bx = blockIdx.x;               // b*128 + tile
    const int b = bx >> 7, l0 = (bx & 127) * 32;
    const int t = threadIdx.x;
    const int j = t & 31, g = t >> 5;        // g 0..7
    const int l = l0 + j;
    const u16x8* y0p = (const u16x8*)(ybuf + ((size_t)(0 + b) * 4096 + l) * 128);
    const u16x8* y1p = (const u16x8*)(ybuf + ((size_t)(4 + b) * 4096 + l) * 128);
    const u16x8* y2p = (const u16x8*)(ybuf + ((size_t)(8 + b) * 4096 + l) * 128);
    const u16x8* y3p = (const u16x8*)(ybuf + ((size_t)(12 + b) * 4096 + l) * 128);
    float vr[128];
    float s1 = 0.f, s2 = 0.f;
#pragma unroll
    for (int g8 = 0; g8 < 16; ++g8) {
        const u16x8 a0 = y0p[g8], a1 = y1p[g8], a2 = y2p[g8], a3 = y3p[g8];
#pragma unroll
        for (int e = 0; e < 8; ++e) {
            const float f = (b2f(a0[e]) + b2f(a1[e])) + (b2f(a2[e]) + b2f(a3[e]));
            vr[g8 * 8 + e] = f;
            s1 += f; s2 = fmaf(f, f, s2);
        }
    }
    const float mu = s1 * (1.f / 128.f);
    const float var = s2 * (1.f / 128.f) - mu * mu;
    const float rstd = rsqrtf(var + 1e-5f);
    const float4* zp = (const float4*)(z + ((size_t)(b * 4096 + l)) * 128);
    const float4* gp = (const float4*)ong;
    const float4* bp = (const float4*)onb;
#pragma unroll
    for (int d4 = 0; d4 < 32; ++d4) {
        const float4 gg = gp[d4], bb = bp[d4], zz = zp[d4];
#define GATE(E, IDX)                                                          \
        {                                                                     \
            const float yln = (vr[d4 * 4 + IDX] - mu) * rstd * gg.E + bb.E;   \
            vr[d4 * 4 + IDX] = yln * (zz.E / (1.f + __expf(-zz.E)));          \
        }
        GATE(x, 0) GATE(y, 1) GATE(z, 2) GATE(w, 3)
#undef GATE
    }
    float acc[8] = {0.f, 0.f, 0.f, 0.f, 0.f, 0.f, 0.f, 0.f};
    for (int d4 = 0; d4 < 32; ++d4) {
#pragma unroll
        for (int q = 0; q < 8; ++q) {
            const float4 wv = *(const float4*)&opw[(size_t)(g * 8 + q) * 128 + d4 * 4];
            acc[q] = fmaf(vr[d4 * 4 + 0], wv.x, acc[q]);
            acc[q] = fmaf(vr[d4 * 4 + 1], wv.y, acc[q]);
            acc[q] = fmaf(vr[d4 * 4 + 2], wv.z, acc[q]);
            acc[q] = fmaf(vr[d4 * 4 + 3], wv.w, acc[q]);
        }
    }
    __shared__ float sres[64 * 33];
#pragma unroll
    for (int q = 0; q < 8; ++q) sres[(g * 8 + q) * 33 + j] = acc[q];
    __syncthreads();
    const float sk = skipp[0];
    for (int e = t; e < 2048; e += 256) {
        const int co = e >> 5, jj = e & 31;
        const size_t o = ((size_t)(b * 64 + co)) * 4096 + l0 + jj;
        res[o] = sres[co * 33 + jj] + sk * x1[o];
    }
}

// ---------------------------------------------------------------------------
// Workspace layout (floats), ~77.4 MB (regions unchanged; xin_s/xin_T/
// xin_raw now bf16 inside their slots):
//   x1 @0 (1M), xin_s @1M (bf16 in 2M slot), zbuf @3M (2M),
//   xin_T @5M (bf16 in 2M slot), xdbl @7,340,032 (2,359,296),
//   ybuf @9,699,328 (bf16), hseg @13,893,632 (2M), pseg @15,990,784 (2M),
//   G @18,087,936 (2M): conv chain / xin_raw(bf16 in G0) / res+tmp,
//   wbf @20,185,088 (81,920), stats @20,267,008 (1024)
// ---------------------------------------------------------------------------
extern "C" void kernel_launch(void* const* d_in, const int* in_sizes, int n_in,
                              void* d_out, int out_size, void* d_ws, size_t ws_size,
                              hipStream_t stream)
{
    const float* x          = (const float*)d_in[0];
    const float* conv1_w    = (const float*)d_in[1];
    const float* conv1_b    = (const float*)d_in[2];
    const float* conv2_w    = (const float*)d_in[3];
    const float* conv2_b    = (const float*)d_in[4];
    const float* cf_w       = (const float*)d_in[5];
    const float* cf_b       = (const float*)d_in[6];
    const float* ln_g       = (const float*)d_in[7];
    const float* ln_b       = (const float*)d_in[8];
    const float* in_proj_w  = (const float*)d_in[9];
    const float* dw_w       = (const float*)d_in[10];
    const float* dw_b       = (const float*)d_in[11];
    const float* x_proj_w   = (const float*)d_in[12];
    const float* dt_proj_w  = (const float*)d_in[13];
    const float* dt_proj_b  = (const float*)d_in[14];
    const float* A_logs     = (const float*)d_in[15];
    const float* Ds         = (const float*)d_in[16];
    const float* out_norm_g = (const float*)d_in[17];
    const float* out_norm_b = (const float*)d_in[18];
    const float* out_proj_w = (const float*)d_in[19];
    const float* skip_scale = (const float*)d_in[20];
    const float* cb_w       = (const float*)d_in[21];
    const float* cb_b       = (const float*)d_in[22];

    float* ws = (float*)d_ws;
    float* x1    = ws;                       // 1,048,576
    u16* xin_s   = (u16*)(ws + 1048576);     // bf16, 2,097,152 elems
    float* zbuf  = ws + 3145728;             // 2,097,152
    u16* xin_T   = (u16*)(ws + 5242880);     // bf16, 2,097,152 elems
    float* xdbl  = ws + 7340032;             // 2,359,296
    u16* ybuf    = (u16*)(ws + 9699328);     // bf16 [k][b][l][d]
    float* hseg  = ws + 13893632;            // 2,097,152
    float* pseg  = ws + 15990784;            // 2,097,152
    float* G     = ws + 18087936;            // 2,097,152 scratch
    float* G0 = G;
    float* G1 = G + 1048576;
    u16* xinraw  = (u16*)G0;                 // bf16, 2,097,152 elems (4 MB)
    short* wbf  = (short*)(ws + 20185088);   // 163,840 bf16
    short* wbf1 = wbf;
    short* wbf2 = wbf + 36864;
    short* wbf3 = wbf + 73728;
    short* wbf4 = wbf + 110592;
    short* wip  = wbf + 147456;
    float* stats1 = ws + 20267008;           // 512 (conv1 out stats)
    float* stats2 = ws + 20267520;           // 512 (cb out stats)

    hipMemsetAsync(stats1, 0, 1024 * sizeof(float), stream);

    wconv_k<<<640, 256, 0, stream>>>(conv1_w, conv2_w, cf_w, cb_w, in_proj_w, wbf);

    conv3x3_mfma_k<<<256, 256, 0, stream>>>(x, wbf1, conv1_b, nullptr,
                                            nullptr, stats1, G0);
    conv3x3_mfma_k<<<256, 256, 0, stream>>>(G0, wbf2, conv2_b, nullptr,
                                            stats1, nullptr, G1);
    conv3x3_mfma_k<<<256, 256, 0, stream>>>(G1, wbf3, cf_b, nullptr,
                                            nullptr, nullptr, x1);
    ln_inproj_mfma_k<<<512, 256, 0, stream>>>(x1, ln_g, ln_b, wip, xinraw, zbuf);
    dwconv_silu_T_k<<<512, 256, 0, stream>>>(xinraw, dw_w, dw_b, xin_s, xin_T);
    xdbl_k<<<2048, 256, 0, stream>>>(xin_s, xin_T, x_proj_w, xdbl);
    scan_p1_k<<<8192, 256, 0, stream>>>(xdbl, xin_s, xin_T, A_logs, dt_proj_w,
                                        dt_proj_b, hseg, pseg);
    scan_combine_k<<<128, 256, 0, stream>>>(hseg, pseg /*-> hstart*/);
    scan_p2_k<<<8192, 256, 0, stream>>>(xdbl, xin_s, xin_T, A_logs, dt_proj_w,
                                        dt_proj_b, pseg /*hstart*/, Ds, ybuf);
    finalize_k<<<512, 256, 0, stream>>>(ybuf, zbuf, x1, out_norm_g, out_norm_b,
                                        out_proj_w, skip_scale, G0 /*res*/);
    conv3x3_mfma_k<<<256, 256, 0, stream>>>(G0 /*res*/, wbf4, cb_b, x1,
                                            nullptr, stats2, G1 /*tmp*/);
    inorm_apply_k<<<256, 256, 0, stream>>>(G1 /*tmp*/, stats2, (float*)d_out);
}